// Round 2
// baseline (3750.467 us; speedup 1.0000x reference)
//
#include <hip/hip_runtime.h>

#define B_ 1024
#define N_ 64
#define T_ 256
#define FB_ 5
#define T2_ 128
#define C_ 128  // 2N

typedef unsigned short u16;
typedef __attribute__((ext_vector_type(8))) short bf16x8;
typedef __attribute__((ext_vector_type(4))) float f32x4;

__device__ __forceinline__ float leaky(float x) { return x >= 0.f ? x : 0.01f * x; }
__device__ __forceinline__ float rcpf(float x) { return __builtin_amdgcn_rcpf(x); }
__device__ __forceinline__ float sigm2(float x) { return rcpf(1.f + __expf(-x)); }
__device__ __forceinline__ float tanh2(float x) { return 1.f - 2.f * rcpf(1.f + __expf(2.f * x)); }
__device__ __forceinline__ unsigned bf16_rne(float f) {
  unsigned u = __float_as_uint(f);
  return (u + 0x7FFFu + ((u >> 16) & 1u)) >> 16;
}
// barrier that does NOT drain vmcnt (keeps global prefetch in flight)
__device__ __forceinline__ void block_sync_lds() {
  __builtin_amdgcn_sched_barrier(0);
  asm volatile("s_waitcnt lgkmcnt(0)" ::: "memory");
  __builtin_amdgcn_s_barrier();
  __builtin_amdgcn_sched_barrier(0);
}

// ---------------- norm_adj: Hn = D^-1/2 (A*(1-I)+I) D^-1/2 ----------------
__global__ void knorm(const float* __restrict__ A, float* __restrict__ Hn) {
  __shared__ float Hs[64][65];
  __shared__ float dinv[64];
  int b = blockIdx.x, t = threadIdx.x;
  const float* Ab = A + (size_t)b * 4096;
  for (int i = 0; i < 64; ++i) {
    float v = Ab[i * 64 + t];
    Hs[i][t] = (i == t) ? 1.f : v;
  }
  __syncthreads();
  float s = 0.f;
  for (int j = 0; j < 64; ++j) s += Hs[t][j];
  dinv[t] = 1.f / sqrtf(s);
  __syncthreads();
  float dt = dinv[t];
  float* Hb = Hn + (size_t)b * 4096;
  for (int i = 0; i < 64; ++i) Hb[i * 64 + t] = dinv[i] * Hs[i][t] * dt;
}

// ------------- Xc+transpose: Xp[b][t][i] = leaky(w * sum_j Hn[b][i][j]*X[b][j][t]) -------------
__global__ void kxc(const float* __restrict__ Hn, const float* __restrict__ X,
                    const float* __restrict__ wsc, float* __restrict__ Xp, int S) {
  __shared__ float Hs[64][65];
  __shared__ float xs[64][68];
  int b = blockIdx.x, t0 = blockIdx.y * 64, tid = threadIdx.x;
  const float* Hb = Hn + (size_t)b * 4096;
  for (int idx = tid; idx < 4096; idx += 256) Hs[idx >> 6][idx & 63] = Hb[idx];
  const float* Xb = X + (size_t)b * 64 * S;
  for (int idx = tid; idx < 4096; idx += 256) {
    int j = idx >> 6, tt = idx & 63;
    xs[j][tt] = (t0 + tt < S) ? Xb[j * S + t0 + tt] : 0.f;
  }
  __syncthreads();
  int i = tid & 63, tg = tid >> 6;
  float w = wsc[0];
  f32x4 acc[4] = {{0, 0, 0, 0}, {0, 0, 0, 0}, {0, 0, 0, 0}, {0, 0, 0, 0}};
  for (int j = 0; j < 64; ++j) {
    float hv = Hs[i][j];
    const f32x4* xr = (const f32x4*)&xs[j][tg * 16];
#pragma unroll
    for (int u = 0; u < 4; ++u) acc[u] += hv * xr[u];
  }
  float* Ob = Xp + (size_t)b * S * 64;
#pragma unroll
  for (int u = 0; u < 4; ++u)
#pragma unroll
    for (int e = 0; e < 4; ++e) {
      int t = t0 + tg * 16 + u * 4 + e;
      if (t < S) Ob[(size_t)t * 64 + i] = leaky(w * acc[u][e]);
    }
}

// -------- repack Xp -> bf16 hi/lo MFMA B-fragments --------
// Xf unit layout: ((bt*S+t)*2+kh)*2+hl blocks of 64 lanes * 8 ushorts
__global__ void kxq(const float* __restrict__ Xp, int S, u16* __restrict__ Xf) {
  __shared__ float xs[4][16][68];
  int bt = blockIdx.x, t0 = blockIdx.y * 4, tid = threadIdx.x;
  for (int idx = tid; idx < 1024; idx += 256) {
    int b_l = idx >> 6, rest = idx & 63, t_l = rest >> 4, c = rest & 15;
    float4 v = {0.f, 0.f, 0.f, 0.f};
    if (t0 + t_l < S)
      v = *(const float4*)(Xp + ((size_t)(bt * 16 + b_l) * S + t0 + t_l) * 64 + c * 4);
    *(float4*)&xs[t_l][b_l][c * 4] = v;
  }
  __syncthreads();
  int t_l = tid >> 6, lane = tid & 63, blo = lane & 15, grp = lane >> 4;
  int t = t0 + t_l;
  if (t >= S) return;
#pragma unroll
  for (int kh = 0; kh < 2; ++kh) {
    const f32x4* src = (const f32x4*)&xs[t_l][blo][kh * 32 + grp * 8];
    f32x4 a0 = src[0], a1 = src[1];
    bf16x8 hi, lo;
#pragma unroll
    for (int e = 0; e < 4; ++e) {
      unsigned h0 = bf16_rne(a0[e]);
      hi[e] = (short)h0;
      lo[e] = (short)bf16_rne(a0[e] - __uint_as_float(h0 << 16));
      unsigned h1 = bf16_rne(a1[e]);
      hi[e + 4] = (short)h1;
      lo[e + 4] = (short)bf16_rne(a1[e] - __uint_as_float(h1 << 16));
    }
    u16* dst = Xf + (size_t)(bt * S + t) * 2048 + (size_t)kh * 1024 + lane * 8;
    *(bf16x8*)dst = hi;
    *(bf16x8*)(dst + 512) = lo;
  }
}

// ---------------- MFMA bidirectional GRU ----------------
// block = (bt: 16 batches, dir). 4 waves; wave w owns gate tiles 3w..3w+2.
// 3xbf16 split on weights and h for ~fp32 accuracy. g output stored bf16.
__global__ __launch_bounds__(256, 1) void kgru2(
    const u16* __restrict__ Xf, int S,
    const float* __restrict__ wih_f, const float* __restrict__ whh_f,
    const float* __restrict__ bih_f, const float* __restrict__ bhh_f,
    const float* __restrict__ wih_b, const float* __restrict__ whh_b,
    const float* __restrict__ bih_b, const float* __restrict__ bhh_b,
    u16* __restrict__ g) {
  __shared__ float S_s[16][132];
  __shared__ float NX_s[16][68];
  __shared__ float NH_s[16][68];
  __shared__ u16 Hhi[16][72];
  __shared__ u16 Hlo[16][72];
  int tid = threadIdx.x;
  int w = tid >> 6, lane = tid & 63, blo = lane & 15, grp = lane >> 4;
  int bt = blockIdx.x, dir = blockIdx.y;
  const float* wih = dir ? wih_b : wih_f;
  const float* whh = dir ? whh_b : whh_f;
  const float* bih = dir ? bih_b : bih_f;
  const float* bhh = dir ? bhh_b : bhh_f;

  // zero h fragment buffers
  for (int idx = tid; idx < 16 * 72; idx += 256) {
    ((u16*)Hhi)[idx] = 0;
    ((u16*)Hlo)[idx] = 0;
  }

  // weight fragments (A operand: row = k = tile*16 + (lane&15), k-dim = kh*32 + grp*8 + e)
  bf16x8 Wih_hi[3][2], Wih_lo[3][2], Whh_hi[3][2], Whh_lo[3][2];
#pragma unroll
  for (int tt = 0; tt < 3; ++tt) {
    int k = (3 * w + tt) * 16 + blo;
#pragma unroll
    for (int kh = 0; kh < 2; ++kh) {
      int j0 = kh * 32 + grp * 8;
#pragma unroll
      for (int m = 0; m < 2; ++m) {
        const float* src = (m ? whh : wih) + (size_t)k * 64 + j0;
        f32x4 a0 = *(const f32x4*)src;
        f32x4 a1 = *(const f32x4*)(src + 4);
        bf16x8 hi, lo;
#pragma unroll
        for (int e = 0; e < 4; ++e) {
          unsigned h0 = bf16_rne(a0[e]);
          hi[e] = (short)h0;
          lo[e] = (short)bf16_rne(a0[e] - __uint_as_float(h0 << 16));
          unsigned h1 = bf16_rne(a1[e]);
          hi[e + 4] = (short)h1;
          lo[e + 4] = (short)bf16_rne(a1[e] - __uint_as_float(h1 << 16));
        }
        if (m) {
          Whh_hi[tt][kh] = hi;
          Whh_lo[tt][kh] = lo;
        } else {
          Wih_hi[tt][kh] = hi;
          Wih_lo[tt][kh] = lo;
        }
      }
    }
  }
  // biases in C layout
  f32x4 bihv[3], bhhv[3];
#pragma unroll
  for (int tt = 0; tt < 3; ++tt) {
    int k0 = (3 * w + tt) * 16 + 4 * grp;
    bihv[tt] = *(const f32x4*)(bih + k0);
    bhhv[tt] = *(const f32x4*)(bhh + k0);
  }

  float ho[4] = {0.f, 0.f, 0.f, 0.f};
  int j0q = 16 * w + 4 * grp;

  bf16x8 xbufA[4], xbufB[4];
  {
    int tr0 = dir ? (S - 1) : 0;
    const u16* xp = Xf + (size_t)(bt * S + tr0) * 2048 + lane * 8;
    xbufA[0] = *(const bf16x8*)(xp);
    xbufA[1] = *(const bf16x8*)(xp + 512);
    xbufA[2] = *(const bf16x8*)(xp + 1024);
    xbufA[3] = *(const bf16x8*)(xp + 1536);
  }
  block_sync_lds();

  auto step = [&](bf16x8(&cur)[4], bf16x8(&nxt)[4], int t) {
    // prefetch x for t+1 (stays in flight across barriers)
    if (t + 1 < S) {
      int trn = dir ? (S - 2 - t) : (t + 1);
      const u16* xp = Xf + (size_t)(bt * S + trn) * 2048 + lane * 8;
      nxt[0] = *(const bf16x8*)(xp);
      nxt[1] = *(const bf16x8*)(xp + 512);
      nxt[2] = *(const bf16x8*)(xp + 1024);
      nxt[3] = *(const bf16x8*)(xp + 1536);
    }
    // h fragments (B operand)
    bf16x8 hfr[4];
    hfr[0] = *(const bf16x8*)&Hhi[blo][grp * 8];
    hfr[1] = *(const bf16x8*)&Hlo[blo][grp * 8];
    hfr[2] = *(const bf16x8*)&Hhi[blo][32 + grp * 8];
    hfr[3] = *(const bf16x8*)&Hlo[blo][32 + grp * 8];
#pragma unroll
    for (int tt = 0; tt < 3; ++tt) {
      f32x4 ax = bihv[tt], ah = bhhv[tt];
#pragma unroll
      for (int kh = 0; kh < 2; ++kh) {
        ax = __builtin_amdgcn_mfma_f32_16x16x32_bf16(Wih_hi[tt][kh], cur[kh * 2 + 0], ax, 0, 0, 0);
        ax = __builtin_amdgcn_mfma_f32_16x16x32_bf16(Wih_hi[tt][kh], cur[kh * 2 + 1], ax, 0, 0, 0);
        ax = __builtin_amdgcn_mfma_f32_16x16x32_bf16(Wih_lo[tt][kh], cur[kh * 2 + 0], ax, 0, 0, 0);
        ah = __builtin_amdgcn_mfma_f32_16x16x32_bf16(Whh_hi[tt][kh], hfr[kh * 2 + 0], ah, 0, 0, 0);
        ah = __builtin_amdgcn_mfma_f32_16x16x32_bf16(Whh_hi[tt][kh], hfr[kh * 2 + 1], ah, 0, 0, 0);
        ah = __builtin_amdgcn_mfma_f32_16x16x32_bf16(Whh_lo[tt][kh], hfr[kh * 2 + 0], ah, 0, 0, 0);
      }
      int tile = 3 * w + tt;
      int k0 = tile * 16 + 4 * grp;
      if (tile < 8) {
        f32x4 sv = ax + ah;
        *(f32x4*)&S_s[blo][k0] = sv;
      } else {
        *(f32x4*)&NX_s[blo][k0 - 128] = ax;
        *(f32x4*)&NH_s[blo][k0 - 128] = ah;
      }
    }
    block_sync_lds();
    // phase B: gates -> h for j in [16w, 16w+16)
    f32x4 rv = *(const f32x4*)&S_s[blo][j0q];
    f32x4 zv = *(const f32x4*)&S_s[blo][64 + j0q];
    f32x4 nx = *(const f32x4*)&NX_s[blo][j0q];
    f32x4 nh = *(const f32x4*)&NH_s[blo][j0q];
    u16 hi_u[4], lo_u[4];
#pragma unroll
    for (int u = 0; u < 4; ++u) {
      float r = sigm2(rv[u]);
      float z = sigm2(zv[u]);
      float n = tanh2(nx[u] + r * nh[u]);
      float h = (1.f - z) * n + z * ho[u];
      ho[u] = h;
      unsigned hb = bf16_rne(h);
      hi_u[u] = (u16)hb;
      lo_u[u] = (u16)bf16_rne(h - __uint_as_float(hb << 16));
    }
    ushort4 h4;
    h4.x = hi_u[0]; h4.y = hi_u[1]; h4.z = hi_u[2]; h4.w = hi_u[3];
    ushort4 l4;
    l4.x = lo_u[0]; l4.y = lo_u[1]; l4.z = lo_u[2]; l4.w = lo_u[3];
    int tr = dir ? (S - 1 - t) : t;
    *(ushort4*)(g + ((size_t)(bt * 16 + blo) * S + tr) * 128 + dir * 64 + j0q) = h4;
    *(ushort4*)&Hhi[blo][j0q] = h4;
    *(ushort4*)&Hlo[blo][j0q] = l4;
    block_sync_lds();
  };

  int t = 0;
  while (t < S) {
    step(xbufA, xbufB, t);
    ++t;
    if (t >= S) break;
    step(xbufB, xbufA, t);
    ++t;
  }
}

// ---------------- BN(train) stats -> per-channel scale/shift ----------------
__global__ void kbn(const u16* __restrict__ g, int S,
                    const float* __restrict__ gamma, const float* __restrict__ beta,
                    float* __restrict__ sd) {
  int t = blockIdx.x, tid = threadIdx.x;
  float s = 0.f, s2 = 0.f;
  for (int unit = tid; unit < 32768; unit += 256) {
    int b = unit >> 5, c4 = (unit & 31) * 4;
    ushort4 u = *(const ushort4*)(g + ((size_t)b * S + t) * 128 + c4);
    float v0 = __uint_as_float((unsigned)u.x << 16);
    float v1 = __uint_as_float((unsigned)u.y << 16);
    float v2 = __uint_as_float((unsigned)u.z << 16);
    float v3 = __uint_as_float((unsigned)u.w << 16);
    s += v0 + v1 + v2 + v3;
    s2 += v0 * v0 + v1 * v1 + v2 * v2 + v3 * v3;
  }
  __shared__ float rs[256], rq[256];
  rs[tid] = s;
  rq[tid] = s2;
  __syncthreads();
  for (int off = 128; off; off >>= 1) {
    if (tid < off) {
      rs[tid] += rs[tid + off];
      rq[tid] += rq[tid + off];
    }
    __syncthreads();
  }
  if (tid == 0) {
    float inv_n = 1.f / (float)(B_ * C_);
    float m = rs[0] * inv_n;
    float var = rq[0] * inv_n - m * m;
    float inv = 1.f / sqrtf(var + 1e-5f);
    float sc = gamma[t] * inv;
    sd[2 * t] = sc;
    sd[2 * t + 1] = beta[t] - m * sc;
  }
}

// -------- M_T[o][t][c] = sum_t2 W1[o][16384 + c*128 + t2] * linT_w[t2][t] --------
__global__ void kMT(const float* __restrict__ W1, const float* __restrict__ lw,
                    float* __restrict__ MT) {
  __shared__ float W1s[128][129];
  __shared__ float ls[128][32];
  int o = blockIdx.x, t0 = blockIdx.y * 32, tid = threadIdx.x;
  const float* Wo = W1 + (size_t)o * 32768 + 16384;
  for (int idx = tid; idx < 16384; idx += 256) W1s[idx >> 7][idx & 127] = Wo[idx];
  for (int idx = tid; idx < 4096; idx += 256)
    ls[idx >> 5][idx & 31] = lw[(idx >> 5) * 256 + t0 + (idx & 31)];
  __syncthreads();
  int c = tid & 127, th = tid >> 7;
  float acc[16];
#pragma unroll
  for (int q = 0; q < 16; ++q) acc[q] = 0.f;
  for (int t2 = 0; t2 < 128; ++t2) {
    float w = W1s[c][t2];
#pragma unroll
    for (int q = 0; q < 16; ++q) acc[q] += w * ls[t2][th + 2 * q];
  }
  float* Mo = MT + (size_t)o * 32768;
#pragma unroll
  for (int q = 0; q < 16; ++q) Mo[(t0 + th + 2 * q) * 128 + c] = acc[q];
}

// -------- M_F[o][f][c] = sum_t2 W1[o][c*128 + t2] * linF_w[t2][f] --------
__global__ void kMF(const float* __restrict__ W1, const float* __restrict__ lw,
                    float* __restrict__ MF) {
  __shared__ float W1s[128][129];
  __shared__ float ls[128][8];
  int o = blockIdx.x, tid = threadIdx.x;
  const float* Wo = W1 + (size_t)o * 32768;
  for (int idx = tid; idx < 16384; idx += 256) W1s[idx >> 7][idx & 127] = Wo[idx];
  for (int idx = tid; idx < 640; idx += 256) ls[idx / 5][idx % 5] = lw[idx];
  __syncthreads();
  int c = tid & 127, fh = tid >> 7;
  float acc[3] = {0.f, 0.f, 0.f};
  for (int t2 = 0; t2 < 128; ++t2) {
    float w = W1s[c][t2];
#pragma unroll
    for (int q = 0; q < 3; ++q) {
      int f = fh + 2 * q;
      if (f < 5) acc[q] += w * ls[t2][f];
    }
  }
#pragma unroll
  for (int q = 0; q < 3; ++q) {
    int f = fh + 2 * q;
    if (f < 5) MF[(size_t)o * 640 + f * 128 + c] = acc[q];
  }
}

// -------- c0[o] = lin1_b[o] + sum_idx W1F*linF_b + W1T*linT_b --------
__global__ void kc0(const float* __restrict__ W1, const float* __restrict__ lFb,
                    const float* __restrict__ lTb, const float* __restrict__ l1b,
                    float* __restrict__ c0) {
  int o = blockIdx.x, tid = threadIdx.x;
  const float* Wo = W1 + (size_t)o * 32768;
  float s = 0.f;
  for (int idx = tid; idx < 16384; idx += 256) {
    int t2 = idx & 127;
    s += Wo[idx] * lFb[t2] + Wo[16384 + idx] * lTb[t2];
  }
  __shared__ float rs[256];
  rs[tid] = s;
  __syncthreads();
  for (int off = 128; off; off >>= 1) {
    if (tid < off) rs[tid] += rs[tid + off];
    __syncthreads();
  }
  if (tid == 0) c0[o] = l1b[o] + rs[0];
}

// -------- partial[slot][b][o] = sum_{t in chunk, c} (g*s_t+d_t) * M[o][t][c] --------
__global__ void kchunk(const u16* __restrict__ g, int S, int nt,
                       const float* __restrict__ sd, const float* __restrict__ M,
                       float* __restrict__ part, int slot0) {
  __shared__ float gs[32][132];
  __shared__ float Ms[64][132];
  int tid = threadIdx.x;
  int b0 = blockIdx.x * 32;
  int t0 = blockIdx.y * nt;
  int slot = slot0 + blockIdx.y;
  int ot = tid & 31, bt = tid >> 5;
  float acc[4][2];
#pragma unroll
  for (int i = 0; i < 4; ++i) {
    acc[i][0] = 0.f;
    acc[i][1] = 0.f;
  }
  for (int t = t0; t < t0 + nt; ++t) {
    __syncthreads();
    float sc = sd[2 * t], dd = sd[2 * t + 1];
    for (int idx = tid; idx < 1024; idx += 256) {
      int bb = idx >> 5, c4 = (idx & 31) * 4;
      ushort4 u = *(const ushort4*)(g + ((size_t)(b0 + bb) * S + t) * 128 + c4);
      gs[bb][c4 + 0] = __uint_as_float((unsigned)u.x << 16) * sc + dd;
      gs[bb][c4 + 1] = __uint_as_float((unsigned)u.y << 16) * sc + dd;
      gs[bb][c4 + 2] = __uint_as_float((unsigned)u.z << 16) * sc + dd;
      gs[bb][c4 + 3] = __uint_as_float((unsigned)u.w << 16) * sc + dd;
    }
    for (int idx = tid; idx < 2048; idx += 256) {
      int o = idx >> 5, c4 = (idx & 31) * 4;
      *(float4*)&Ms[o][c4] = *(const float4*)(M + ((size_t)o * S + t) * 128 + c4);
    }
    __syncthreads();
    for (int c = 0; c < 128; c += 4) {
      f32x4 m0 = *(const f32x4*)&Ms[ot][c];
      f32x4 m1 = *(const f32x4*)&Ms[ot + 32][c];
#pragma unroll
      for (int i = 0; i < 4; ++i) {
        f32x4 gv = *(const f32x4*)&gs[bt * 4 + i][c];
        acc[i][0] += gv[0] * m0[0] + gv[1] * m0[1] + gv[2] * m0[2] + gv[3] * m0[3];
        acc[i][1] += gv[0] * m1[0] + gv[1] * m1[1] + gv[2] * m1[2] + gv[3] * m1[3];
      }
    }
  }
#pragma unroll
  for (int i = 0; i < 4; ++i) {
    part[((size_t)slot * 1024 + b0 + bt * 4 + i) * 64 + ot] = acc[i][0];
    part[((size_t)slot * 1024 + b0 + bt * 4 + i) * 64 + ot + 32] = acc[i][1];
  }
}

// -------- finalize: y = leaky(sum partials + c0); out = y @ lin2^T + b2 --------
__global__ void kfin(const float* __restrict__ part, const float* __restrict__ c0,
                     const float* __restrict__ l2w, const float* __restrict__ l2b,
                     float* __restrict__ outp) {
  int b = blockIdx.x, o = threadIdx.x;
  float y = c0[o];
  for (int s = 0; s < 17; ++s) y += part[((size_t)s * 1024 + b) * 64 + o];
  y = leaky(y);
  __shared__ float a[64];
  a[o] = y;
  __syncthreads();
  if (o < 3) {
    float r = l2b[o];
    for (int j = 0; j < 64; ++j) r += l2w[o * 64 + j] * a[j];
    outp[b * 3 + o] = r;
  }
}

extern "C" void kernel_launch(void* const* d_in, const int* in_sizes, int n_in,
                              void* d_out, int out_size, void* d_ws, size_t ws_size,
                              hipStream_t stream) {
  const float* x_T = (const float*)d_in[0];
  const float* x_F = (const float*)d_in[1];
  const float* A = (const float*)d_in[2];
  const float* gcnw_F = (const float*)d_in[3];
  const float* gFwih_f = (const float*)d_in[4];
  const float* gFwhh_f = (const float*)d_in[5];
  const float* gFbih_f = (const float*)d_in[6];
  const float* gFbhh_f = (const float*)d_in[7];
  const float* gFwih_b = (const float*)d_in[8];
  const float* gFwhh_b = (const float*)d_in[9];
  const float* gFbih_b = (const float*)d_in[10];
  const float* gFbhh_b = (const float*)d_in[11];
  const float* bnFg = (const float*)d_in[12];
  const float* bnFb = (const float*)d_in[13];
  const float* gcnw_T = (const float*)d_in[14];
  const float* gTwih_f = (const float*)d_in[15];
  const float* gTwhh_f = (const float*)d_in[16];
  const float* gTbih_f = (const float*)d_in[17];
  const float* gTbhh_f = (const float*)d_in[18];
  const float* gTwih_b = (const float*)d_in[19];
  const float* gTwhh_b = (const float*)d_in[20];
  const float* gTbih_b = (const float*)d_in[21];
  const float* gTbhh_b = (const float*)d_in[22];
  const float* bnTg = (const float*)d_in[23];
  const float* bnTb = (const float*)d_in[24];
  const float* linF_w = (const float*)d_in[25];
  const float* linF_b = (const float*)d_in[26];
  const float* linT_w = (const float*)d_in[27];
  const float* linT_b = (const float*)d_in[28];
  const float* lin1_w = (const float*)d_in[29];
  const float* lin1_b = (const float*)d_in[30];
  const float* lin2_w = (const float*)d_in[31];
  const float* lin2_b = (const float*)d_in[32];

  char* w8 = (char*)d_ws;
  size_t off = 0;
  auto take = [&](size_t bytes) {
    void* p = w8 + off;
    off += (bytes + 255) & ~(size_t)255;
    return p;
  };
  float* Hn = (float*)take((size_t)1024 * 4096 * 4);
  float* XpT = (float*)take((size_t)1024 * 256 * 64 * 4);
  float* XpF = (float*)take((size_t)1024 * 5 * 64 * 4);
  u16* XfT = (u16*)take((size_t)64 * 256 * 2048 * 2);
  u16* XfF = (u16*)take((size_t)64 * 5 * 2048 * 2);
  u16* gT = (u16*)take((size_t)1024 * 256 * 128 * 2);
  u16* gF = (u16*)take((size_t)1024 * 5 * 128 * 2);
  float* sdT = (float*)take(512 * 4);
  float* sdF = (float*)take(16 * 4);
  float* MT = (float*)take((size_t)64 * 256 * 128 * 4);
  float* MF = (float*)take((size_t)64 * 5 * 128 * 4);
  float* c0 = (float*)take(64 * 4);
  float* part = (float*)take((size_t)17 * 1024 * 64 * 4);

  knorm<<<1024, 64, 0, stream>>>(A, Hn);
  kxc<<<dim3(1024, 4), 256, 0, stream>>>(Hn, x_T, gcnw_T, XpT, 256);
  kxc<<<dim3(1024, 1), 256, 0, stream>>>(Hn, x_F, gcnw_F, XpF, 5);
  kxq<<<dim3(64, 64), 256, 0, stream>>>(XpT, 256, XfT);
  kxq<<<dim3(64, 2), 256, 0, stream>>>(XpF, 5, XfF);
  kgru2<<<dim3(64, 2), 256, 0, stream>>>(XfT, 256, gTwih_f, gTwhh_f, gTbih_f, gTbhh_f,
                                         gTwih_b, gTwhh_b, gTbih_b, gTbhh_b, gT);
  kgru2<<<dim3(64, 2), 256, 0, stream>>>(XfF, 5, gFwih_f, gFwhh_f, gFbih_f, gFbhh_f,
                                         gFwih_b, gFwhh_b, gFbih_b, gFbhh_b, gF);
  kbn<<<256, 256, 0, stream>>>(gT, 256, bnTg, bnTb, sdT);
  kbn<<<5, 256, 0, stream>>>(gF, 5, bnFg, bnFb, sdF);
  kMT<<<dim3(64, 8), 256, 0, stream>>>(lin1_w, linT_w, MT);
  kMF<<<64, 256, 0, stream>>>(lin1_w, linF_w, MF);
  kc0<<<64, 256, 0, stream>>>(lin1_w, linF_b, linT_b, lin1_b, c0);
  kchunk<<<dim3(32, 16), 256, 0, stream>>>(gT, 256, 16, sdT, MT, part, 0);
  kchunk<<<dim3(32, 1), 256, 0, stream>>>(gF, 5, 5, sdF, MF, part, 16);
  kfin<<<1024, 64, 0, stream>>>(part, c0, lin2_w, lin2_b, (float*)d_out);
}

// Round 3
// 1749.158 us; speedup vs baseline: 2.1442x; 2.1442x over previous
//
#include <hip/hip_runtime.h>

#define B_ 1024
#define N_ 64
#define T_ 256
#define FB_ 5
#define T2_ 128
#define C_ 128  // 2N

typedef unsigned short u16;
typedef __attribute__((ext_vector_type(8))) short bf16x8;
typedef __attribute__((ext_vector_type(4))) float f32x4;

__device__ __forceinline__ float leaky(float x) { return x >= 0.f ? x : 0.01f * x; }
__device__ __forceinline__ float rcpf(float x) { return __builtin_amdgcn_rcpf(x); }
__device__ __forceinline__ float sigm2(float x) { return rcpf(1.f + __expf(-x)); }
__device__ __forceinline__ float tanh2(float x) { return 1.f - 2.f * rcpf(1.f + __expf(2.f * x)); }
__device__ __forceinline__ unsigned bf16_rne(float f) {
  unsigned u = __float_as_uint(f);
  return (u + 0x7FFFu + ((u >> 16) & 1u)) >> 16;
}
// barrier that does NOT drain vmcnt (keeps global prefetch in flight)
__device__ __forceinline__ void block_sync_lds() {
  __builtin_amdgcn_sched_barrier(0);
  asm volatile("s_waitcnt lgkmcnt(0)" ::: "memory");
  __builtin_amdgcn_s_barrier();
  __builtin_amdgcn_sched_barrier(0);
}

// ---------------- norm_adj: Hn = D^-1/2 (A*(1-I)+I) D^-1/2 ----------------
__global__ void knorm(const float* __restrict__ A, float* __restrict__ Hn) {
  __shared__ float Hs[64][65];
  __shared__ float dinv[64];
  int b = blockIdx.x, t = threadIdx.x;
  const float* Ab = A + (size_t)b * 4096;
  for (int i = 0; i < 64; ++i) {
    float v = Ab[i * 64 + t];
    Hs[i][t] = (i == t) ? 1.f : v;
  }
  __syncthreads();
  float s = 0.f;
  for (int j = 0; j < 64; ++j) s += Hs[t][j];
  dinv[t] = 1.f / sqrtf(s);
  __syncthreads();
  float dt = dinv[t];
  float* Hb = Hn + (size_t)b * 4096;
  for (int i = 0; i < 64; ++i) Hb[i * 64 + t] = dinv[i] * Hs[i][t] * dt;
}

// ------------- Xc+transpose: Xp[b][t][i] = leaky(w * sum_j Hn[b][i][j]*X[b][j][t]) -------------
// (round-1 scalar form: known-good codegen, no scratch spill)
__global__ void kxc(const float* __restrict__ Hn, const float* __restrict__ X,
                    const float* __restrict__ wsc, float* __restrict__ Xp, int S) {
  __shared__ float Hs[64][65];
  __shared__ float xs[64][65];
  int b = blockIdx.x, t0 = blockIdx.y * 64, tid = threadIdx.x;
  const float* Hb = Hn + (size_t)b * 4096;
  for (int idx = tid; idx < 4096; idx += 256) Hs[idx >> 6][idx & 63] = Hb[idx];
  const float* Xb = X + (size_t)b * 64 * S;
  for (int idx = tid; idx < 4096; idx += 256) {
    int j = idx >> 6, tt = idx & 63;
    xs[j][tt] = (t0 + tt < S) ? Xb[j * S + t0 + tt] : 0.f;
  }
  __syncthreads();
  int i = tid & 63, tg = tid >> 6;
  float w = wsc[0];
  float acc[16];
#pragma unroll
  for (int q = 0; q < 16; ++q) acc[q] = 0.f;
  for (int j = 0; j < 64; ++j) {
    float hv = Hs[i][j];
#pragma unroll
    for (int q = 0; q < 16; ++q) acc[q] += hv * xs[j][tg * 16 + q];
  }
  float* Ob = Xp + (size_t)b * S * 64;
#pragma unroll
  for (int q = 0; q < 16; ++q) {
    int t = t0 + tg * 16 + q;
    if (t < S) Ob[(size_t)t * 64 + i] = leaky(w * acc[q]);
  }
}

// -------- repack Xp -> bf16 hi/lo MFMA B-fragments --------
// Xf unit layout: ((bt*S+t)*2+kh)*2+hl blocks of 64 lanes * 8 ushorts
__global__ void kxq(const float* __restrict__ Xp, int S, u16* __restrict__ Xf) {
  __shared__ float xs[4][16][68];
  int bt = blockIdx.x, t0 = blockIdx.y * 4, tid = threadIdx.x;
  for (int idx = tid; idx < 1024; idx += 256) {
    int b_l = idx >> 6, rest = idx & 63, t_l = rest >> 4, c = rest & 15;
    float4 v = {0.f, 0.f, 0.f, 0.f};
    if (t0 + t_l < S)
      v = *(const float4*)(Xp + ((size_t)(bt * 16 + b_l) * S + t0 + t_l) * 64 + c * 4);
    *(float4*)&xs[t_l][b_l][c * 4] = v;
  }
  __syncthreads();
  int t_l = tid >> 6, lane = tid & 63, blo = lane & 15, grp = lane >> 4;
  int t = t0 + t_l;
  if (t >= S) return;
#pragma unroll
  for (int kh = 0; kh < 2; ++kh) {
    const f32x4* src = (const f32x4*)&xs[t_l][blo][kh * 32 + grp * 8];
    f32x4 a0 = src[0], a1 = src[1];
    bf16x8 hi, lo;
#pragma unroll
    for (int e = 0; e < 4; ++e) {
      unsigned h0 = bf16_rne(a0[e]);
      hi[e] = (short)h0;
      lo[e] = (short)bf16_rne(a0[e] - __uint_as_float(h0 << 16));
      unsigned h1 = bf16_rne(a1[e]);
      hi[e + 4] = (short)h1;
      lo[e + 4] = (short)bf16_rne(a1[e] - __uint_as_float(h1 << 16));
    }
    u16* dst = Xf + (size_t)(bt * S + t) * 2048 + (size_t)kh * 1024 + lane * 8;
    *(bf16x8*)dst = hi;
    *(bf16x8*)(dst + 512) = lo;
  }
}

// ---------------- MFMA bidirectional GRU ----------------
// block = (bt: 16 batches, dir). 4 waves; wave w owns gate tiles 3w..3w+2.
// 3xbf16 split on weights and h for ~fp32 accuracy. g output stored bf16.
__global__ __launch_bounds__(256, 1) void kgru2(
    const u16* __restrict__ Xf, int S,
    const float* __restrict__ wih_f, const float* __restrict__ whh_f,
    const float* __restrict__ bih_f, const float* __restrict__ bhh_f,
    const float* __restrict__ wih_b, const float* __restrict__ whh_b,
    const float* __restrict__ bih_b, const float* __restrict__ bhh_b,
    u16* __restrict__ g) {
  __shared__ float S_s[16][132];
  __shared__ float NX_s[16][68];
  __shared__ float NH_s[16][68];
  __shared__ u16 Hhi[16][72];
  __shared__ u16 Hlo[16][72];
  int tid = threadIdx.x;
  int w = tid >> 6, lane = tid & 63, blo = lane & 15, grp = lane >> 4;
  int bt = blockIdx.x, dir = blockIdx.y;
  const float* wih = dir ? wih_b : wih_f;
  const float* whh = dir ? whh_b : whh_f;
  const float* bih = dir ? bih_b : bih_f;
  const float* bhh = dir ? bhh_b : bhh_f;

  // zero h fragment buffers
  for (int idx = tid; idx < 16 * 72; idx += 256) {
    ((u16*)Hhi)[idx] = 0;
    ((u16*)Hlo)[idx] = 0;
  }

  // weight fragments (A operand: row = k = tile*16 + (lane&15), k-dim = kh*32 + grp*8 + e)
  bf16x8 Wih_hi[3][2], Wih_lo[3][2], Whh_hi[3][2], Whh_lo[3][2];
#pragma unroll
  for (int tt = 0; tt < 3; ++tt) {
    int k = (3 * w + tt) * 16 + blo;
#pragma unroll
    for (int kh = 0; kh < 2; ++kh) {
      int j0 = kh * 32 + grp * 8;
#pragma unroll
      for (int m = 0; m < 2; ++m) {
        const float* src = (m ? whh : wih) + (size_t)k * 64 + j0;
        f32x4 a0 = *(const f32x4*)src;
        f32x4 a1 = *(const f32x4*)(src + 4);
        bf16x8 hi, lo;
#pragma unroll
        for (int e = 0; e < 4; ++e) {
          unsigned h0 = bf16_rne(a0[e]);
          hi[e] = (short)h0;
          lo[e] = (short)bf16_rne(a0[e] - __uint_as_float(h0 << 16));
          unsigned h1 = bf16_rne(a1[e]);
          hi[e + 4] = (short)h1;
          lo[e + 4] = (short)bf16_rne(a1[e] - __uint_as_float(h1 << 16));
        }
        if (m) {
          Whh_hi[tt][kh] = hi;
          Whh_lo[tt][kh] = lo;
        } else {
          Wih_hi[tt][kh] = hi;
          Wih_lo[tt][kh] = lo;
        }
      }
    }
  }
  // biases in C layout
  f32x4 bihv[3], bhhv[3];
#pragma unroll
  for (int tt = 0; tt < 3; ++tt) {
    int k0 = (3 * w + tt) * 16 + 4 * grp;
    bihv[tt] = *(const f32x4*)(bih + k0);
    bhhv[tt] = *(const f32x4*)(bhh + k0);
  }

  float ho[4] = {0.f, 0.f, 0.f, 0.f};
  int j0q = 16 * w + 4 * grp;

  bf16x8 xbufA[4], xbufB[4];
  {
    int tr0 = dir ? (S - 1) : 0;
    const u16* xp = Xf + (size_t)(bt * S + tr0) * 2048 + lane * 8;
    xbufA[0] = *(const bf16x8*)(xp);
    xbufA[1] = *(const bf16x8*)(xp + 512);
    xbufA[2] = *(const bf16x8*)(xp + 1024);
    xbufA[3] = *(const bf16x8*)(xp + 1536);
  }
  block_sync_lds();

  auto step = [&](bf16x8(&cur)[4], bf16x8(&nxt)[4], int t) {
    // prefetch x for t+1 (stays in flight across barriers)
    if (t + 1 < S) {
      int trn = dir ? (S - 2 - t) : (t + 1);
      const u16* xp = Xf + (size_t)(bt * S + trn) * 2048 + lane * 8;
      nxt[0] = *(const bf16x8*)(xp);
      nxt[1] = *(const bf16x8*)(xp + 512);
      nxt[2] = *(const bf16x8*)(xp + 1024);
      nxt[3] = *(const bf16x8*)(xp + 1536);
    }
    // h fragments (B operand)
    bf16x8 hfr[4];
    hfr[0] = *(const bf16x8*)&Hhi[blo][grp * 8];
    hfr[1] = *(const bf16x8*)&Hlo[blo][grp * 8];
    hfr[2] = *(const bf16x8*)&Hhi[blo][32 + grp * 8];
    hfr[3] = *(const bf16x8*)&Hlo[blo][32 + grp * 8];
#pragma unroll
    for (int tt = 0; tt < 3; ++tt) {
      f32x4 ax = bihv[tt], ah = bhhv[tt];
#pragma unroll
      for (int kh = 0; kh < 2; ++kh) {
        ax = __builtin_amdgcn_mfma_f32_16x16x32_bf16(Wih_hi[tt][kh], cur[kh * 2 + 0], ax, 0, 0, 0);
        ax = __builtin_amdgcn_mfma_f32_16x16x32_bf16(Wih_hi[tt][kh], cur[kh * 2 + 1], ax, 0, 0, 0);
        ax = __builtin_amdgcn_mfma_f32_16x16x32_bf16(Wih_lo[tt][kh], cur[kh * 2 + 0], ax, 0, 0, 0);
        ah = __builtin_amdgcn_mfma_f32_16x16x32_bf16(Whh_hi[tt][kh], hfr[kh * 2 + 0], ah, 0, 0, 0);
        ah = __builtin_amdgcn_mfma_f32_16x16x32_bf16(Whh_hi[tt][kh], hfr[kh * 2 + 1], ah, 0, 0, 0);
        ah = __builtin_amdgcn_mfma_f32_16x16x32_bf16(Whh_lo[tt][kh], hfr[kh * 2 + 0], ah, 0, 0, 0);
      }
      int tile = 3 * w + tt;
      int k0 = tile * 16 + 4 * grp;
      if (tile < 8) {
        f32x4 sv = ax + ah;
        *(f32x4*)&S_s[blo][k0] = sv;
      } else {
        *(f32x4*)&NX_s[blo][k0 - 128] = ax;
        *(f32x4*)&NH_s[blo][k0 - 128] = ah;
      }
    }
    block_sync_lds();
    // phase B: gates -> h for j in [16w, 16w+16)
    f32x4 rv = *(const f32x4*)&S_s[blo][j0q];
    f32x4 zv = *(const f32x4*)&S_s[blo][64 + j0q];
    f32x4 nx = *(const f32x4*)&NX_s[blo][j0q];
    f32x4 nh = *(const f32x4*)&NH_s[blo][j0q];
    u16 hi_u[4], lo_u[4];
#pragma unroll
    for (int u = 0; u < 4; ++u) {
      float r = sigm2(rv[u]);
      float z = sigm2(zv[u]);
      float n = tanh2(nx[u] + r * nh[u]);
      float h = (1.f - z) * n + z * ho[u];
      ho[u] = h;
      unsigned hb = bf16_rne(h);
      hi_u[u] = (u16)hb;
      lo_u[u] = (u16)bf16_rne(h - __uint_as_float(hb << 16));
    }
    ushort4 h4;
    h4.x = hi_u[0]; h4.y = hi_u[1]; h4.z = hi_u[2]; h4.w = hi_u[3];
    ushort4 l4;
    l4.x = lo_u[0]; l4.y = lo_u[1]; l4.z = lo_u[2]; l4.w = lo_u[3];
    int tr = dir ? (S - 1 - t) : t;
    *(ushort4*)(g + ((size_t)(bt * 16 + blo) * S + tr) * 128 + dir * 64 + j0q) = h4;
    *(ushort4*)&Hhi[blo][j0q] = h4;
    *(ushort4*)&Hlo[blo][j0q] = l4;
    block_sync_lds();
  };

  int t = 0;
  while (t < S) {
    step(xbufA, xbufB, t);
    ++t;
    if (t >= S) break;
    step(xbufB, xbufA, t);
    ++t;
  }
}

// ---------------- BN(train) stats -> per-channel scale/shift ----------------
__global__ void kbn(const u16* __restrict__ g, int S,
                    const float* __restrict__ gamma, const float* __restrict__ beta,
                    float* __restrict__ sd) {
  int t = blockIdx.x, tid = threadIdx.x;
  float s = 0.f, s2 = 0.f;
  for (int unit = tid; unit < 32768; unit += 256) {
    int b = unit >> 5, c4 = (unit & 31) * 4;
    ushort4 u = *(const ushort4*)(g + ((size_t)b * S + t) * 128 + c4);
    float v0 = __uint_as_float((unsigned)u.x << 16);
    float v1 = __uint_as_float((unsigned)u.y << 16);
    float v2 = __uint_as_float((unsigned)u.z << 16);
    float v3 = __uint_as_float((unsigned)u.w << 16);
    s += v0 + v1 + v2 + v3;
    s2 += v0 * v0 + v1 * v1 + v2 * v2 + v3 * v3;
  }
  __shared__ float rs[256], rq[256];
  rs[tid] = s;
  rq[tid] = s2;
  __syncthreads();
  for (int off = 128; off; off >>= 1) {
    if (tid < off) {
      rs[tid] += rs[tid + off];
      rq[tid] += rq[tid + off];
    }
    __syncthreads();
  }
  if (tid == 0) {
    float inv_n = 1.f / (float)(B_ * C_);
    float m = rs[0] * inv_n;
    float var = rq[0] * inv_n - m * m;
    float inv = 1.f / sqrtf(var + 1e-5f);
    float sc = gamma[t] * inv;
    sd[2 * t] = sc;
    sd[2 * t + 1] = beta[t] - m * sc;
  }
}

// -------- M_T[o][t][c] = sum_t2 W1[o][16384 + c*128 + t2] * linT_w[t2][t] --------
__global__ void kMT(const float* __restrict__ W1, const float* __restrict__ lw,
                    float* __restrict__ MT) {
  __shared__ float W1s[128][129];
  __shared__ float ls[128][32];
  int o = blockIdx.x, t0 = blockIdx.y * 32, tid = threadIdx.x;
  const float* Wo = W1 + (size_t)o * 32768 + 16384;
  for (int idx = tid; idx < 16384; idx += 256) W1s[idx >> 7][idx & 127] = Wo[idx];
  for (int idx = tid; idx < 4096; idx += 256)
    ls[idx >> 5][idx & 31] = lw[(idx >> 5) * 256 + t0 + (idx & 31)];
  __syncthreads();
  int c = tid & 127, th = tid >> 7;
  float acc[16];
#pragma unroll
  for (int q = 0; q < 16; ++q) acc[q] = 0.f;
  for (int t2 = 0; t2 < 128; ++t2) {
    float w = W1s[c][t2];
#pragma unroll
    for (int q = 0; q < 16; ++q) acc[q] += w * ls[t2][th + 2 * q];
  }
  float* Mo = MT + (size_t)o * 32768;
#pragma unroll
  for (int q = 0; q < 16; ++q) Mo[(t0 + th + 2 * q) * 128 + c] = acc[q];
}

// -------- M_F[o][f][c] = sum_t2 W1[o][c*128 + t2] * linF_w[t2][f] --------
__global__ void kMF(const float* __restrict__ W1, const float* __restrict__ lw,
                    float* __restrict__ MF) {
  __shared__ float W1s[128][129];
  __shared__ float ls[128][8];
  int o = blockIdx.x, tid = threadIdx.x;
  const float* Wo = W1 + (size_t)o * 32768;
  for (int idx = tid; idx < 16384; idx += 256) W1s[idx >> 7][idx & 127] = Wo[idx];
  for (int idx = tid; idx < 640; idx += 256) ls[idx / 5][idx % 5] = lw[idx];
  __syncthreads();
  int c = tid & 127, fh = tid >> 7;
  float acc[3] = {0.f, 0.f, 0.f};
  for (int t2 = 0; t2 < 128; ++t2) {
    float w = W1s[c][t2];
#pragma unroll
    for (int q = 0; q < 3; ++q) {
      int f = fh + 2 * q;
      if (f < 5) acc[q] += w * ls[t2][f];
    }
  }
#pragma unroll
  for (int q = 0; q < 3; ++q) {
    int f = fh + 2 * q;
    if (f < 5) MF[(size_t)o * 640 + f * 128 + c] = acc[q];
  }
}

// -------- c0[o] = lin1_b[o] + sum_idx W1F*linF_b + W1T*linT_b --------
__global__ void kc0(const float* __restrict__ W1, const float* __restrict__ lFb,
                    const float* __restrict__ lTb, const float* __restrict__ l1b,
                    float* __restrict__ c0) {
  int o = blockIdx.x, tid = threadIdx.x;
  const float* Wo = W1 + (size_t)o * 32768;
  float s = 0.f;
  for (int idx = tid; idx < 16384; idx += 256) {
    int t2 = idx & 127;
    s += Wo[idx] * lFb[t2] + Wo[16384 + idx] * lTb[t2];
  }
  __shared__ float rs[256];
  rs[tid] = s;
  __syncthreads();
  for (int off = 128; off; off >>= 1) {
    if (tid < off) rs[tid] += rs[tid + off];
    __syncthreads();
  }
  if (tid == 0) c0[o] = l1b[o] + rs[0];
}

// -------- partial[slot][b][o] = sum_{t in chunk, c} (g*s_t+d_t) * M[o][t][c] --------
__global__ void kchunk(const u16* __restrict__ g, int S, int nt,
                       const float* __restrict__ sd, const float* __restrict__ M,
                       float* __restrict__ part, int slot0) {
  __shared__ float gs[32][132];
  __shared__ float Ms[64][132];
  int tid = threadIdx.x;
  int b0 = blockIdx.x * 32;
  int t0 = blockIdx.y * nt;
  int slot = slot0 + blockIdx.y;
  int ot = tid & 31, bt = tid >> 5;
  float acc[4][2];
#pragma unroll
  for (int i = 0; i < 4; ++i) {
    acc[i][0] = 0.f;
    acc[i][1] = 0.f;
  }
  for (int t = t0; t < t0 + nt; ++t) {
    __syncthreads();
    float sc = sd[2 * t], dd = sd[2 * t + 1];
    for (int idx = tid; idx < 1024; idx += 256) {
      int bb = idx >> 5, c4 = (idx & 31) * 4;
      ushort4 u = *(const ushort4*)(g + ((size_t)(b0 + bb) * S + t) * 128 + c4);
      gs[bb][c4 + 0] = __uint_as_float((unsigned)u.x << 16) * sc + dd;
      gs[bb][c4 + 1] = __uint_as_float((unsigned)u.y << 16) * sc + dd;
      gs[bb][c4 + 2] = __uint_as_float((unsigned)u.z << 16) * sc + dd;
      gs[bb][c4 + 3] = __uint_as_float((unsigned)u.w << 16) * sc + dd;
    }
    for (int idx = tid; idx < 2048; idx += 256) {
      int o = idx >> 5, c4 = (idx & 31) * 4;
      *(float4*)&Ms[o][c4] = *(const float4*)(M + ((size_t)o * S + t) * 128 + c4);
    }
    __syncthreads();
    for (int c = 0; c < 128; c += 4) {
      f32x4 m0 = *(const f32x4*)&Ms[ot][c];
      f32x4 m1 = *(const f32x4*)&Ms[ot + 32][c];
#pragma unroll
      for (int i = 0; i < 4; ++i) {
        f32x4 gv = *(const f32x4*)&gs[bt * 4 + i][c];
        acc[i][0] += gv[0] * m0[0] + gv[1] * m0[1] + gv[2] * m0[2] + gv[3] * m0[3];
        acc[i][1] += gv[0] * m1[0] + gv[1] * m1[1] + gv[2] * m1[2] + gv[3] * m1[3];
      }
    }
  }
#pragma unroll
  for (int i = 0; i < 4; ++i) {
    part[((size_t)slot * 1024 + b0 + bt * 4 + i) * 64 + ot] = acc[i][0];
    part[((size_t)slot * 1024 + b0 + bt * 4 + i) * 64 + ot + 32] = acc[i][1];
  }
}

// -------- finalize: y = leaky(sum partials + c0); out = y @ lin2^T + b2 --------
__global__ void kfin(const float* __restrict__ part, const float* __restrict__ c0,
                     const float* __restrict__ l2w, const float* __restrict__ l2b,
                     float* __restrict__ outp) {
  int b = blockIdx.x, o = threadIdx.x;
  float y = c0[o];
  for (int s = 0; s < 17; ++s) y += part[((size_t)s * 1024 + b) * 64 + o];
  y = leaky(y);
  __shared__ float a[64];
  a[o] = y;
  __syncthreads();
  if (o < 3) {
    float r = l2b[o];
    for (int j = 0; j < 64; ++j) r += l2w[o * 64 + j] * a[j];
    outp[b * 3 + o] = r;
  }
}

extern "C" void kernel_launch(void* const* d_in, const int* in_sizes, int n_in,
                              void* d_out, int out_size, void* d_ws, size_t ws_size,
                              hipStream_t stream) {
  const float* x_T = (const float*)d_in[0];
  const float* x_F = (const float*)d_in[1];
  const float* A = (const float*)d_in[2];
  const float* gcnw_F = (const float*)d_in[3];
  const float* gFwih_f = (const float*)d_in[4];
  const float* gFwhh_f = (const float*)d_in[5];
  const float* gFbih_f = (const float*)d_in[6];
  const float* gFbhh_f = (const float*)d_in[7];
  const float* gFwih_b = (const float*)d_in[8];
  const float* gFwhh_b = (const float*)d_in[9];
  const float* gFbih_b = (const float*)d_in[10];
  const float* gFbhh_b = (const float*)d_in[11];
  const float* bnFg = (const float*)d_in[12];
  const float* bnFb = (const float*)d_in[13];
  const float* gcnw_T = (const float*)d_in[14];
  const float* gTwih_f = (const float*)d_in[15];
  const float* gTwhh_f = (const float*)d_in[16];
  const float* gTbih_f = (const float*)d_in[17];
  const float* gTbhh_f = (const float*)d_in[18];
  const float* gTwih_b = (const float*)d_in[19];
  const float* gTwhh_b = (const float*)d_in[20];
  const float* gTbih_b = (const float*)d_in[21];
  const float* gTbhh_b = (const float*)d_in[22];
  const float* bnTg = (const float*)d_in[23];
  const float* bnTb = (const float*)d_in[24];
  const float* linF_w = (const float*)d_in[25];
  const float* linF_b = (const float*)d_in[26];
  const float* linT_w = (const float*)d_in[27];
  const float* linT_b = (const float*)d_in[28];
  const float* lin1_w = (const float*)d_in[29];
  const float* lin1_b = (const float*)d_in[30];
  const float* lin2_w = (const float*)d_in[31];
  const float* lin2_b = (const float*)d_in[32];

  char* w8 = (char*)d_ws;
  size_t off = 0;
  auto take = [&](size_t bytes) {
    void* p = w8 + off;
    off += (bytes + 255) & ~(size_t)255;
    return p;
  };
  float* Hn = (float*)take((size_t)1024 * 4096 * 4);
  float* XpT = (float*)take((size_t)1024 * 256 * 64 * 4);
  float* XpF = (float*)take((size_t)1024 * 5 * 64 * 4);
  u16* XfT = (u16*)take((size_t)64 * 256 * 2048 * 2);
  u16* XfF = (u16*)take((size_t)64 * 5 * 2048 * 2);
  u16* gT = (u16*)take((size_t)1024 * 256 * 128 * 2);
  u16* gF = (u16*)take((size_t)1024 * 5 * 128 * 2);
  float* sdT = (float*)take(512 * 4);
  float* sdF = (float*)take(16 * 4);
  float* MT = (float*)take((size_t)64 * 256 * 128 * 4);
  float* MF = (float*)take((size_t)64 * 5 * 128 * 4);
  float* c0 = (float*)take(64 * 4);
  float* part = (float*)take((size_t)17 * 1024 * 64 * 4);

  knorm<<<1024, 64, 0, stream>>>(A, Hn);
  kxc<<<dim3(1024, 4), 256, 0, stream>>>(Hn, x_T, gcnw_T, XpT, 256);
  kxc<<<dim3(1024, 1), 256, 0, stream>>>(Hn, x_F, gcnw_F, XpF, 5);
  kxq<<<dim3(64, 64), 256, 0, stream>>>(XpT, 256, XfT);
  kxq<<<dim3(64, 2), 256, 0, stream>>>(XpF, 5, XfF);
  kgru2<<<dim3(64, 2), 256, 0, stream>>>(XfT, 256, gTwih_f, gTwhh_f, gTbih_f, gTbhh_f,
                                         gTwih_b, gTwhh_b, gTbih_b, gTbhh_b, gT);
  kgru2<<<dim3(64, 2), 256, 0, stream>>>(XfF, 5, gFwih_f, gFwhh_f, gFbih_f, gFbhh_f,
                                         gFwih_b, gFwhh_b, gFbih_b, gFbhh_b, gF);
  kbn<<<256, 256, 0, stream>>>(gT, 256, bnTg, bnTb, sdT);
  kbn<<<5, 256, 0, stream>>>(gF, 5, bnFg, bnFb, sdF);
  kMT<<<dim3(64, 8), 256, 0, stream>>>(lin1_w, linT_w, MT);
  kMF<<<64, 256, 0, stream>>>(lin1_w, linF_w, MF);
  kc0<<<64, 256, 0, stream>>>(lin1_w, linF_b, linT_b, lin1_b, c0);
  kchunk<<<dim3(32, 16), 256, 0, stream>>>(gT, 256, 16, sdT, MT, part, 0);
  kchunk<<<dim3(32, 1), 256, 0, stream>>>(gF, 5, 5, sdF, MF, part, 16);
  kfin<<<1024, 64, 0, stream>>>(part, c0, lin2_w, lin2_b, (float*)d_out);
}

// Round 4
// 758.439 us; speedup vs baseline: 4.9450x; 2.3063x over previous
//
#include <hip/hip_runtime.h>

#define B_ 1024
#define N_ 64
#define T_ 256
#define FB_ 5
#define T2_ 128
#define C_ 128  // 2N

typedef unsigned short u16;
typedef __attribute__((ext_vector_type(8))) short bf16x8;
typedef __attribute__((ext_vector_type(4))) float f32x4;

__device__ __forceinline__ float leaky(float x) { return x >= 0.f ? x : 0.01f * x; }
__device__ __forceinline__ float rcpf(float x) { return __builtin_amdgcn_rcpf(x); }
__device__ __forceinline__ float sigm2(float x) { return rcpf(1.f + __expf(-x)); }
__device__ __forceinline__ float tanh2(float x) { return 1.f - 2.f * rcpf(1.f + __expf(2.f * x)); }
__device__ __forceinline__ unsigned bf16_rne(float f) {
  unsigned u = __float_as_uint(f);
  return (u + 0x7FFFu + ((u >> 16) & 1u)) >> 16;
}
// barrier that does NOT drain vmcnt (keeps global prefetch in flight)
__device__ __forceinline__ void block_sync_lds() {
  __builtin_amdgcn_sched_barrier(0);
  asm volatile("s_waitcnt lgkmcnt(0)" ::: "memory");
  __builtin_amdgcn_s_barrier();
  __builtin_amdgcn_sched_barrier(0);
}

// ---------------- norm_adj: Hn = D^-1/2 (A*(1-I)+I) D^-1/2 ----------------
__global__ __launch_bounds__(64) void knorm(const float* __restrict__ A, float* __restrict__ Hn) {
  __shared__ float Hs[64][65];
  __shared__ float dinv[64];
  int b = blockIdx.x, t = threadIdx.x;
  const float* Ab = A + (size_t)b * 4096;
  for (int i = 0; i < 64; ++i) {
    float v = Ab[i * 64 + t];
    Hs[i][t] = (i == t) ? 1.f : v;
  }
  __syncthreads();
  float s = 0.f;
  for (int j = 0; j < 64; ++j) s += Hs[t][j];
  dinv[t] = 1.f / sqrtf(s);
  __syncthreads();
  float dt = dinv[t];
  float* Hb = Hn + (size_t)b * 4096;
  for (int i = 0; i < 64; ++i) Hb[i * 64 + t] = dinv[i] * Hs[i][t] * dt;
}

// ------------- Xc+transpose: Xp[b][t][i] = leaky(w * sum_j Hn[b][i][j]*X[b][j][t]) -------------
__global__ __launch_bounds__(256) void kxc(const float* __restrict__ Hn, const float* __restrict__ X,
                    const float* __restrict__ wsc, float* __restrict__ Xp, int S) {
  __shared__ float Hs[64][65];
  __shared__ float xs[64][65];
  int b = blockIdx.x, t0 = blockIdx.y * 64, tid = threadIdx.x;
  const float* Hb = Hn + (size_t)b * 4096;
  for (int idx = tid; idx < 4096; idx += 256) Hs[idx >> 6][idx & 63] = Hb[idx];
  const float* Xb = X + (size_t)b * 64 * S;
  for (int idx = tid; idx < 4096; idx += 256) {
    int j = idx >> 6, tt = idx & 63;
    xs[j][tt] = (t0 + tt < S) ? Xb[j * S + t0 + tt] : 0.f;
  }
  __syncthreads();
  int i = tid & 63, tg = tid >> 6;
  float w = wsc[0];
  float acc[16];
#pragma unroll
  for (int q = 0; q < 16; ++q) acc[q] = 0.f;
  for (int j = 0; j < 64; ++j) {
    float hv = Hs[i][j];
#pragma unroll
    for (int q = 0; q < 16; ++q) acc[q] += hv * xs[j][tg * 16 + q];
  }
  float* Ob = Xp + (size_t)b * S * 64;
#pragma unroll
  for (int q = 0; q < 16; ++q) {
    int t = t0 + tg * 16 + q;
    if (t < S) Ob[(size_t)t * 64 + i] = leaky(w * acc[q]);
  }
}

// -------- repack Xp -> bf16 hi/lo MFMA B-fragments --------
// Xf unit layout: ((bt*S+t)*2+kh)*2+hl blocks of 64 lanes * 8 ushorts
__global__ __launch_bounds__(256) void kxq(const float* __restrict__ Xp, int S, u16* __restrict__ Xf) {
  __shared__ float xs[4][16][68];
  int bt = blockIdx.x, t0 = blockIdx.y * 4, tid = threadIdx.x;
  for (int idx = tid; idx < 1024; idx += 256) {
    int b_l = idx >> 6, rest = idx & 63, t_l = rest >> 4, c = rest & 15;
    float4 v = {0.f, 0.f, 0.f, 0.f};
    if (t0 + t_l < S)
      v = *(const float4*)(Xp + ((size_t)(bt * 16 + b_l) * S + t0 + t_l) * 64 + c * 4);
    *(float4*)&xs[t_l][b_l][c * 4] = v;
  }
  __syncthreads();
  int t_l = tid >> 6, lane = tid & 63, blo = lane & 15, grp = lane >> 4;
  int t = t0 + t_l;
  if (t >= S) return;
#pragma unroll
  for (int kh = 0; kh < 2; ++kh) {
    const f32x4* src = (const f32x4*)&xs[t_l][blo][kh * 32 + grp * 8];
    f32x4 a0 = src[0], a1 = src[1];
    bf16x8 hi, lo;
#pragma unroll
    for (int e = 0; e < 4; ++e) {
      unsigned h0 = bf16_rne(a0[e]);
      hi[e] = (short)h0;
      lo[e] = (short)bf16_rne(a0[e] - __uint_as_float(h0 << 16));
      unsigned h1 = bf16_rne(a1[e]);
      hi[e + 4] = (short)h1;
      lo[e + 4] = (short)bf16_rne(a1[e] - __uint_as_float(h1 << 16));
    }
    u16* dst = Xf + (size_t)(bt * S + t) * 2048 + (size_t)kh * 1024 + lane * 8;
    *(bf16x8*)dst = hi;
    *(bf16x8*)(dst + 512) = lo;
  }
}

// ---------------- MFMA bidirectional GRU ----------------
// block = (bt: 16 batches, dir). 4 waves; wave w owns gate tiles 3w..3w+2.
// 3xbf16 split on weights and h for ~fp32 accuracy. g output stored bf16.
__global__ __launch_bounds__(256, 1) void kgru2(
    const u16* __restrict__ Xf, int S,
    const float* __restrict__ wih_f, const float* __restrict__ whh_f,
    const float* __restrict__ bih_f, const float* __restrict__ bhh_f,
    const float* __restrict__ wih_b, const float* __restrict__ whh_b,
    const float* __restrict__ bih_b, const float* __restrict__ bhh_b,
    u16* __restrict__ g) {
  __shared__ float S_s[16][132];
  __shared__ float NX_s[16][68];
  __shared__ float NH_s[16][68];
  __shared__ u16 Hhi[16][72];
  __shared__ u16 Hlo[16][72];
  int tid = threadIdx.x;
  int w = tid >> 6, lane = tid & 63, blo = lane & 15, grp = lane >> 4;
  int bt = blockIdx.x, dir = blockIdx.y;
  const float* wih = dir ? wih_b : wih_f;
  const float* whh = dir ? whh_b : whh_f;
  const float* bih = dir ? bih_b : bih_f;
  const float* bhh = dir ? bhh_b : bhh_f;

  // zero h fragment buffers
  for (int idx = tid; idx < 16 * 72; idx += 256) {
    ((u16*)Hhi)[idx] = 0;
    ((u16*)Hlo)[idx] = 0;
  }

  // weight fragments (A operand: row = k = tile*16 + (lane&15), k-dim = kh*32 + grp*8 + e)
  bf16x8 Wih_hi[3][2], Wih_lo[3][2], Whh_hi[3][2], Whh_lo[3][2];
#pragma unroll
  for (int tt = 0; tt < 3; ++tt) {
    int k = (3 * w + tt) * 16 + blo;
#pragma unroll
    for (int kh = 0; kh < 2; ++kh) {
      int j0 = kh * 32 + grp * 8;
#pragma unroll
      for (int m = 0; m < 2; ++m) {
        const float* src = (m ? whh : wih) + (size_t)k * 64 + j0;
        f32x4 a0 = *(const f32x4*)src;
        f32x4 a1 = *(const f32x4*)(src + 4);
        bf16x8 hi, lo;
#pragma unroll
        for (int e = 0; e < 4; ++e) {
          unsigned h0 = bf16_rne(a0[e]);
          hi[e] = (short)h0;
          lo[e] = (short)bf16_rne(a0[e] - __uint_as_float(h0 << 16));
          unsigned h1 = bf16_rne(a1[e]);
          hi[e + 4] = (short)h1;
          lo[e + 4] = (short)bf16_rne(a1[e] - __uint_as_float(h1 << 16));
        }
        if (m) {
          Whh_hi[tt][kh] = hi;
          Whh_lo[tt][kh] = lo;
        } else {
          Wih_hi[tt][kh] = hi;
          Wih_lo[tt][kh] = lo;
        }
      }
    }
  }
  // biases in C layout
  f32x4 bihv[3], bhhv[3];
#pragma unroll
  for (int tt = 0; tt < 3; ++tt) {
    int k0 = (3 * w + tt) * 16 + 4 * grp;
    bihv[tt] = *(const f32x4*)(bih + k0);
    bhhv[tt] = *(const f32x4*)(bhh + k0);
  }

  float ho[4] = {0.f, 0.f, 0.f, 0.f};
  int j0q = 16 * w + 4 * grp;

  bf16x8 xbufA[4], xbufB[4];
  {
    int tr0 = dir ? (S - 1) : 0;
    const u16* xp = Xf + (size_t)(bt * S + tr0) * 2048 + lane * 8;
    xbufA[0] = *(const bf16x8*)(xp);
    xbufA[1] = *(const bf16x8*)(xp + 512);
    xbufA[2] = *(const bf16x8*)(xp + 1024);
    xbufA[3] = *(const bf16x8*)(xp + 1536);
  }
  block_sync_lds();

  auto step = [&](bf16x8(&cur)[4], bf16x8(&nxt)[4], int t) {
    // prefetch x for t+1 (stays in flight across barriers)
    if (t + 1 < S) {
      int trn = dir ? (S - 2 - t) : (t + 1);
      const u16* xp = Xf + (size_t)(bt * S + trn) * 2048 + lane * 8;
      nxt[0] = *(const bf16x8*)(xp);
      nxt[1] = *(const bf16x8*)(xp + 512);
      nxt[2] = *(const bf16x8*)(xp + 1024);
      nxt[3] = *(const bf16x8*)(xp + 1536);
    }
    // h fragments (B operand)
    bf16x8 hfr[4];
    hfr[0] = *(const bf16x8*)&Hhi[blo][grp * 8];
    hfr[1] = *(const bf16x8*)&Hlo[blo][grp * 8];
    hfr[2] = *(const bf16x8*)&Hhi[blo][32 + grp * 8];
    hfr[3] = *(const bf16x8*)&Hlo[blo][32 + grp * 8];
#pragma unroll
    for (int tt = 0; tt < 3; ++tt) {
      f32x4 ax = bihv[tt], ah = bhhv[tt];
#pragma unroll
      for (int kh = 0; kh < 2; ++kh) {
        ax = __builtin_amdgcn_mfma_f32_16x16x32_bf16(Wih_hi[tt][kh], cur[kh * 2 + 0], ax, 0, 0, 0);
        ax = __builtin_amdgcn_mfma_f32_16x16x32_bf16(Wih_hi[tt][kh], cur[kh * 2 + 1], ax, 0, 0, 0);
        ax = __builtin_amdgcn_mfma_f32_16x16x32_bf16(Wih_lo[tt][kh], cur[kh * 2 + 0], ax, 0, 0, 0);
        ah = __builtin_amdgcn_mfma_f32_16x16x32_bf16(Whh_hi[tt][kh], hfr[kh * 2 + 0], ah, 0, 0, 0);
        ah = __builtin_amdgcn_mfma_f32_16x16x32_bf16(Whh_hi[tt][kh], hfr[kh * 2 + 1], ah, 0, 0, 0);
        ah = __builtin_amdgcn_mfma_f32_16x16x32_bf16(Whh_lo[tt][kh], hfr[kh * 2 + 0], ah, 0, 0, 0);
      }
      int tile = 3 * w + tt;
      int k0 = tile * 16 + 4 * grp;
      if (tile < 8) {
        f32x4 sv = ax + ah;
        *(f32x4*)&S_s[blo][k0] = sv;
      } else {
        *(f32x4*)&NX_s[blo][k0 - 128] = ax;
        *(f32x4*)&NH_s[blo][k0 - 128] = ah;
      }
    }
    block_sync_lds();
    // phase B: gates -> h for j in [16w, 16w+16)
    f32x4 rv = *(const f32x4*)&S_s[blo][j0q];
    f32x4 zv = *(const f32x4*)&S_s[blo][64 + j0q];
    f32x4 nx = *(const f32x4*)&NX_s[blo][j0q];
    f32x4 nh = *(const f32x4*)&NH_s[blo][j0q];
    u16 hi_u[4], lo_u[4];
#pragma unroll
    for (int u = 0; u < 4; ++u) {
      float r = sigm2(rv[u]);
      float z = sigm2(zv[u]);
      float n = tanh2(nx[u] + r * nh[u]);
      float h = (1.f - z) * n + z * ho[u];
      ho[u] = h;
      unsigned hb = bf16_rne(h);
      hi_u[u] = (u16)hb;
      lo_u[u] = (u16)bf16_rne(h - __uint_as_float(hb << 16));
    }
    ushort4 h4;
    h4.x = hi_u[0]; h4.y = hi_u[1]; h4.z = hi_u[2]; h4.w = hi_u[3];
    ushort4 l4;
    l4.x = lo_u[0]; l4.y = lo_u[1]; l4.z = lo_u[2]; l4.w = lo_u[3];
    int tr = dir ? (S - 1 - t) : t;
    *(ushort4*)(g + ((size_t)(bt * 16 + blo) * S + tr) * 128 + dir * 64 + j0q) = h4;
    *(ushort4*)&Hhi[blo][j0q] = h4;
    *(ushort4*)&Hlo[blo][j0q] = l4;
    block_sync_lds();
  };

  int t = 0;
  while (t < S) {
    step(xbufA, xbufB, t);
    ++t;
    if (t >= S) break;
    step(xbufB, xbufA, t);
    ++t;
  }
}

// ---------------- BN(train) stats -> per-channel scale/shift ----------------
__global__ __launch_bounds__(256) void kbn(const u16* __restrict__ g, int S,
                    const float* __restrict__ gamma, const float* __restrict__ beta,
                    float* __restrict__ sd) {
  int t = blockIdx.x, tid = threadIdx.x;
  float s = 0.f, s2 = 0.f;
  for (int unit = tid; unit < 32768; unit += 256) {
    int b = unit >> 5, c4 = (unit & 31) * 4;
    ushort4 u = *(const ushort4*)(g + ((size_t)b * S + t) * 128 + c4);
    float v0 = __uint_as_float((unsigned)u.x << 16);
    float v1 = __uint_as_float((unsigned)u.y << 16);
    float v2 = __uint_as_float((unsigned)u.z << 16);
    float v3 = __uint_as_float((unsigned)u.w << 16);
    s += v0 + v1 + v2 + v3;
    s2 += v0 * v0 + v1 * v1 + v2 * v2 + v3 * v3;
  }
  __shared__ float rs[256], rq[256];
  rs[tid] = s;
  rq[tid] = s2;
  __syncthreads();
  for (int off = 128; off; off >>= 1) {
    if (tid < off) {
      rs[tid] += rs[tid + off];
      rq[tid] += rq[tid + off];
    }
    __syncthreads();
  }
  if (tid == 0) {
    float inv_n = 1.f / (float)(B_ * C_);
    float m = rs[0] * inv_n;
    float var = rq[0] * inv_n - m * m;
    float inv = 1.f / sqrtf(var + 1e-5f);
    float sc = gamma[t] * inv;
    sd[2 * t] = sc;
    sd[2 * t + 1] = beta[t] - m * sc;
  }
}

// -------- M_T[o][t][c] = sum_t2 W1[o][16384 + c*128 + t2] * linT_w[t2][t] --------
__global__ __launch_bounds__(256) void kMT(const float* __restrict__ W1, const float* __restrict__ lw,
                    float* __restrict__ MT) {
  __shared__ float W1s[128][129];
  __shared__ float ls[128][32];
  int o = blockIdx.x, t0 = blockIdx.y * 32, tid = threadIdx.x;
  const float* Wo = W1 + (size_t)o * 32768 + 16384;
  for (int idx = tid; idx < 16384; idx += 256) W1s[idx >> 7][idx & 127] = Wo[idx];
  for (int idx = tid; idx < 4096; idx += 256)
    ls[idx >> 5][idx & 31] = lw[(idx >> 5) * 256 + t0 + (idx & 31)];
  __syncthreads();
  int c = tid & 127, th = tid >> 7;
  float acc[16];
#pragma unroll
  for (int q = 0; q < 16; ++q) acc[q] = 0.f;
  for (int t2 = 0; t2 < 128; ++t2) {
    float w = W1s[c][t2];
#pragma unroll
    for (int q = 0; q < 16; ++q) acc[q] += w * ls[t2][th + 2 * q];
  }
  float* Mo = MT + (size_t)o * 32768;
#pragma unroll
  for (int q = 0; q < 16; ++q) Mo[(t0 + th + 2 * q) * 128 + c] = acc[q];
}

// -------- M_F[o][f][c] = sum_t2 W1[o][c*128 + t2] * linF_w[t2][f] --------
__global__ __launch_bounds__(256) void kMF(const float* __restrict__ W1, const float* __restrict__ lw,
                    float* __restrict__ MF) {
  __shared__ float W1s[128][129];
  __shared__ float ls[128][8];
  int o = blockIdx.x, tid = threadIdx.x;
  const float* Wo = W1 + (size_t)o * 32768;
  for (int idx = tid; idx < 16384; idx += 256) W1s[idx >> 7][idx & 127] = Wo[idx];
  for (int idx = tid; idx < 640; idx += 256) ls[idx / 5][idx % 5] = lw[idx];
  __syncthreads();
  int c = tid & 127, fh = tid >> 7;
  float acc[3] = {0.f, 0.f, 0.f};
  for (int t2 = 0; t2 < 128; ++t2) {
    float w = W1s[c][t2];
#pragma unroll
    for (int q = 0; q < 3; ++q) {
      int f = fh + 2 * q;
      if (f < 5) acc[q] += w * ls[t2][f];
    }
  }
#pragma unroll
  for (int q = 0; q < 3; ++q) {
    int f = fh + 2 * q;
    if (f < 5) MF[(size_t)o * 640 + f * 128 + c] = acc[q];
  }
}

// -------- c0[o] = lin1_b[o] + sum_idx W1F*linF_b + W1T*linT_b --------
__global__ __launch_bounds__(256) void kc0(const float* __restrict__ W1, const float* __restrict__ lFb,
                    const float* __restrict__ lTb, const float* __restrict__ l1b,
                    float* __restrict__ c0) {
  int o = blockIdx.x, tid = threadIdx.x;
  const float* Wo = W1 + (size_t)o * 32768;
  float s = 0.f;
  for (int idx = tid; idx < 16384; idx += 256) {
    int t2 = idx & 127;
    s += Wo[idx] * lFb[t2] + Wo[16384 + idx] * lTb[t2];
  }
  __shared__ float rs[256];
  rs[tid] = s;
  __syncthreads();
  for (int off = 128; off; off >>= 1) {
    if (tid < off) rs[tid] += rs[tid + off];
    __syncthreads();
  }
  if (tid == 0) c0[o] = l1b[o] + rs[0];
}

// -------- partial[slot][b][o] = sum_{t in chunk, c} (g*s_t+d_t) * M[o][t][c] --------
__global__ __launch_bounds__(256) void kchunk(const u16* __restrict__ g, int S, int nt,
                       const float* __restrict__ sd, const float* __restrict__ M,
                       float* __restrict__ part, int slot0) {
  __shared__ float gs[32][132];
  __shared__ float Ms[64][132];
  int tid = threadIdx.x;
  int b0 = blockIdx.x * 32;
  int t0 = blockIdx.y * nt;
  int slot = slot0 + blockIdx.y;
  int ot = tid & 31, bt = tid >> 5;
  float acc[4][2];
#pragma unroll
  for (int i = 0; i < 4; ++i) {
    acc[i][0] = 0.f;
    acc[i][1] = 0.f;
  }
  for (int t = t0; t < t0 + nt; ++t) {
    __syncthreads();
    float sc = sd[2 * t], dd = sd[2 * t + 1];
    for (int idx = tid; idx < 1024; idx += 256) {
      int bb = idx >> 5, c4 = (idx & 31) * 4;
      ushort4 u = *(const ushort4*)(g + ((size_t)(b0 + bb) * S + t) * 128 + c4);
      gs[bb][c4 + 0] = __uint_as_float((unsigned)u.x << 16) * sc + dd;
      gs[bb][c4 + 1] = __uint_as_float((unsigned)u.y << 16) * sc + dd;
      gs[bb][c4 + 2] = __uint_as_float((unsigned)u.z << 16) * sc + dd;
      gs[bb][c4 + 3] = __uint_as_float((unsigned)u.w << 16) * sc + dd;
    }
    for (int idx = tid; idx < 2048; idx += 256) {
      int o = idx >> 5, c4 = (idx & 31) * 4;
      *(float4*)&Ms[o][c4] = *(const float4*)(M + ((size_t)o * S + t) * 128 + c4);
    }
    __syncthreads();
    for (int c = 0; c < 128; c += 4) {
      f32x4 m0 = *(const f32x4*)&Ms[ot][c];
      f32x4 m1 = *(const f32x4*)&Ms[ot + 32][c];
#pragma unroll
      for (int i = 0; i < 4; ++i) {
        f32x4 gv = *(const f32x4*)&gs[bt * 4 + i][c];
        acc[i][0] += gv[0] * m0[0] + gv[1] * m0[1] + gv[2] * m0[2] + gv[3] * m0[3];
        acc[i][1] += gv[0] * m1[0] + gv[1] * m1[1] + gv[2] * m1[2] + gv[3] * m1[3];
      }
    }
  }
#pragma unroll
  for (int i = 0; i < 4; ++i) {
    part[((size_t)slot * 1024 + b0 + bt * 4 + i) * 64 + ot] = acc[i][0];
    part[((size_t)slot * 1024 + b0 + bt * 4 + i) * 64 + ot + 32] = acc[i][1];
  }
}

// -------- finalize: y = leaky(sum partials + c0); out = y @ lin2^T + b2 --------
__global__ __launch_bounds__(64) void kfin(const float* __restrict__ part, const float* __restrict__ c0,
                     const float* __restrict__ l2w, const float* __restrict__ l2b,
                     float* __restrict__ outp) {
  int b = blockIdx.x, o = threadIdx.x;
  float y = c0[o];
  for (int s = 0; s < 17; ++s) y += part[((size_t)s * 1024 + b) * 64 + o];
  y = leaky(y);
  __shared__ float a[64];
  a[o] = y;
  __syncthreads();
  if (o < 3) {
    float r = l2b[o];
    for (int j = 0; j < 64; ++j) r += l2w[o * 64 + j] * a[j];
    outp[b * 3 + o] = r;
  }
}

extern "C" void kernel_launch(void* const* d_in, const int* in_sizes, int n_in,
                              void* d_out, int out_size, void* d_ws, size_t ws_size,
                              hipStream_t stream) {
  const float* x_T = (const float*)d_in[0];
  const float* x_F = (const float*)d_in[1];
  const float* A = (const float*)d_in[2];
  const float* gcnw_F = (const float*)d_in[3];
  const float* gFwih_f = (const float*)d_in[4];
  const float* gFwhh_f = (const float*)d_in[5];
  const float* gFbih_f = (const float*)d_in[6];
  const float* gFbhh_f = (const float*)d_in[7];
  const float* gFwih_b = (const float*)d_in[8];
  const float* gFwhh_b = (const float*)d_in[9];
  const float* gFbih_b = (const float*)d_in[10];
  const float* gFbhh_b = (const float*)d_in[11];
  const float* bnFg = (const float*)d_in[12];
  const float* bnFb = (const float*)d_in[13];
  const float* gcnw_T = (const float*)d_in[14];
  const float* gTwih_f = (const float*)d_in[15];
  const float* gTwhh_f = (const float*)d_in[16];
  const float* gTbih_f = (const float*)d_in[17];
  const float* gTbhh_f = (const float*)d_in[18];
  const float* gTwih_b = (const float*)d_in[19];
  const float* gTwhh_b = (const float*)d_in[20];
  const float* gTbih_b = (const float*)d_in[21];
  const float* gTbhh_b = (const float*)d_in[22];
  const float* bnTg = (const float*)d_in[23];
  const float* bnTb = (const float*)d_in[24];
  const float* linF_w = (const float*)d_in[25];
  const float* linF_b = (const float*)d_in[26];
  const float* linT_w = (const float*)d_in[27];
  const float* linT_b = (const float*)d_in[28];
  const float* lin1_w = (const float*)d_in[29];
  const float* lin1_b = (const float*)d_in[30];
  const float* lin2_w = (const float*)d_in[31];
  const float* lin2_b = (const float*)d_in[32];

  char* w8 = (char*)d_ws;
  size_t off = 0;
  auto take = [&](size_t bytes) {
    void* p = w8 + off;
    off += (bytes + 255) & ~(size_t)255;
    return p;
  };
  float* Hn = (float*)take((size_t)1024 * 4096 * 4);
  float* XpT = (float*)take((size_t)1024 * 256 * 64 * 4);
  float* XpF = (float*)take((size_t)1024 * 5 * 64 * 4);
  u16* XfT = (u16*)take((size_t)64 * 256 * 2048 * 2);
  u16* XfF = (u16*)take((size_t)64 * 5 * 2048 * 2);
  u16* gT = (u16*)take((size_t)1024 * 256 * 128 * 2);
  u16* gF = (u16*)take((size_t)1024 * 5 * 128 * 2);
  float* sdT = (float*)take(512 * 4);
  float* sdF = (float*)take(16 * 4);
  float* MT = (float*)take((size_t)64 * 256 * 128 * 4);
  float* MF = (float*)take((size_t)64 * 5 * 128 * 4);
  float* c0 = (float*)take(64 * 4);
  float* part = (float*)take((size_t)17 * 1024 * 64 * 4);

  knorm<<<1024, 64, 0, stream>>>(A, Hn);
  kxc<<<dim3(1024, 4), 256, 0, stream>>>(Hn, x_T, gcnw_T, XpT, 256);
  kxc<<<dim3(1024, 1), 256, 0, stream>>>(Hn, x_F, gcnw_F, XpF, 5);
  kxq<<<dim3(64, 64), 256, 0, stream>>>(XpT, 256, XfT);
  kxq<<<dim3(64, 2), 256, 0, stream>>>(XpF, 5, XfF);
  kgru2<<<dim3(64, 2), 256, 0, stream>>>(XfT, 256, gTwih_f, gTwhh_f, gTbih_f, gTbhh_f,
                                         gTwih_b, gTwhh_b, gTbih_b, gTbhh_b, gT);
  kgru2<<<dim3(64, 2), 256, 0, stream>>>(XfF, 5, gFwih_f, gFwhh_f, gFbih_f, gFbhh_f,
                                         gFwih_b, gFwhh_b, gFbih_b, gFbhh_b, gF);
  kbn<<<256, 256, 0, stream>>>(gT, 256, bnTg, bnTb, sdT);
  kbn<<<5, 256, 0, stream>>>(gF, 5, bnFg, bnFb, sdF);
  kMT<<<dim3(64, 8), 256, 0, stream>>>(lin1_w, linT_w, MT);
  kMF<<<64, 256, 0, stream>>>(lin1_w, linF_w, MF);
  kc0<<<64, 256, 0, stream>>>(lin1_w, linF_b, linT_b, lin1_b, c0);
  kchunk<<<dim3(32, 16), 256, 0, stream>>>(gT, 256, 16, sdT, MT, part, 0);
  kchunk<<<dim3(32, 1), 256, 0, stream>>>(gF, 5, 5, sdF, MF, part, 16);
  kfin<<<1024, 64, 0, stream>>>(part, c0, lin2_w, lin2_b, (float*)d_out);
}

// Round 5
// 685.289 us; speedup vs baseline: 5.4728x; 1.1067x over previous
//
#include <hip/hip_runtime.h>

#define B_ 1024
#define N_ 64
#define T_ 256
#define FB_ 5
#define T2_ 128
#define C_ 128  // 2N

typedef unsigned short u16;
typedef __attribute__((ext_vector_type(8))) short bf16x8;
typedef __attribute__((ext_vector_type(4))) float f32x4;

__device__ __forceinline__ float leaky(float x) { return x >= 0.f ? x : 0.01f * x; }
__device__ __forceinline__ float rcpf(float x) { return __builtin_amdgcn_rcpf(x); }
__device__ __forceinline__ float sigm2(float x) { return rcpf(1.f + __expf(-x)); }
__device__ __forceinline__ float tanh2(float x) { return 1.f - 2.f * rcpf(1.f + __expf(2.f * x)); }
__device__ __forceinline__ unsigned bf16_rne(float f) {
  unsigned u = __float_as_uint(f);
  return (u + 0x7FFFu + ((u >> 16) & 1u)) >> 16;
}
// barrier that does NOT drain vmcnt (keeps global prefetch in flight)
__device__ __forceinline__ void block_sync_lds() {
  __builtin_amdgcn_sched_barrier(0);
  asm volatile("s_waitcnt lgkmcnt(0)" ::: "memory");
  __builtin_amdgcn_s_barrier();
  __builtin_amdgcn_sched_barrier(0);
}

// ---------------- norm_adj: Hn = D^-1/2 (A*(1-I)+I) D^-1/2 ----------------
__global__ __launch_bounds__(64) void knorm(const float* __restrict__ A, float* __restrict__ Hn) {
  __shared__ float Hs[64][65];
  __shared__ float dinv[64];
  int b = blockIdx.x, t = threadIdx.x;
  const float* Ab = A + (size_t)b * 4096;
  for (int i = 0; i < 64; ++i) {
    float v = Ab[i * 64 + t];
    Hs[i][t] = (i == t) ? 1.f : v;
  }
  __syncthreads();
  float s = 0.f;
  for (int j = 0; j < 64; ++j) s += Hs[t][j];
  dinv[t] = 1.f / sqrtf(s);
  __syncthreads();
  float dt = dinv[t];
  float* Hb = Hn + (size_t)b * 4096;
  for (int i = 0; i < 64; ++i) Hb[i * 64 + t] = dinv[i] * Hs[i][t] * dt;
}

// ------------- Xc+transpose: Xp[b][t][i] = leaky(w * sum_j Hn[b][i][j]*X[b][j][t]) -------------
// xs padded to 68 (16B-aligned rows) for b128 broadcast reads; Hs kept 65 (2-way column reads)
__global__ __launch_bounds__(256) void kxc(const float* __restrict__ Hn, const float* __restrict__ X,
                    const float* __restrict__ wsc, float* __restrict__ Xp, int S) {
  __shared__ float Hs[64][65];
  __shared__ float xs[64][68];
  int b = blockIdx.x, t0 = blockIdx.y * 64, tid = threadIdx.x;
  const float* Hb = Hn + (size_t)b * 4096;
  for (int idx = tid; idx < 4096; idx += 256) Hs[idx >> 6][idx & 63] = Hb[idx];
  const float* Xb = X + (size_t)b * 64 * S;
  for (int idx = tid; idx < 4096; idx += 256) {
    int j = idx >> 6, tt = idx & 63;
    xs[j][tt] = (t0 + tt < S) ? Xb[j * S + t0 + tt] : 0.f;
  }
  __syncthreads();
  int i = tid & 63, tg = tid >> 6;
  float w = wsc[0];
  f32x4 acc0 = {0, 0, 0, 0}, acc1 = {0, 0, 0, 0}, acc2 = {0, 0, 0, 0}, acc3 = {0, 0, 0, 0};
  for (int j = 0; j < 64; ++j) {
    float hv = Hs[i][j];
    const f32x4* xr = (const f32x4*)&xs[j][tg * 16];
    f32x4 x0 = xr[0], x1 = xr[1], x2 = xr[2], x3 = xr[3];
    acc0 += hv * x0;
    acc1 += hv * x1;
    acc2 += hv * x2;
    acc3 += hv * x3;
  }
  float* Ob = Xp + (size_t)b * S * 64;
  float accs[16];
#pragma unroll
  for (int e = 0; e < 4; ++e) {
    accs[e] = acc0[e];
    accs[4 + e] = acc1[e];
    accs[8 + e] = acc2[e];
    accs[12 + e] = acc3[e];
  }
#pragma unroll
  for (int q = 0; q < 16; ++q) {
    int t = t0 + tg * 16 + q;
    if (t < S) Ob[(size_t)t * 64 + i] = leaky(w * accs[q]);
  }
}

// -------- repack Xp -> bf16 hi/lo MFMA B-fragments --------
// Xf unit layout: ((bt*S+t)*2+kh)*2+hl blocks of 64 lanes * 8 ushorts
__global__ __launch_bounds__(256) void kxq(const float* __restrict__ Xp, int S, u16* __restrict__ Xf) {
  __shared__ float xs[4][16][68];
  int bt = blockIdx.x, t0 = blockIdx.y * 4, tid = threadIdx.x;
  for (int idx = tid; idx < 1024; idx += 256) {
    int b_l = idx >> 6, rest = idx & 63, t_l = rest >> 4, c = rest & 15;
    float4 v = {0.f, 0.f, 0.f, 0.f};
    if (t0 + t_l < S)
      v = *(const float4*)(Xp + ((size_t)(bt * 16 + b_l) * S + t0 + t_l) * 64 + c * 4);
    *(float4*)&xs[t_l][b_l][c * 4] = v;
  }
  __syncthreads();
  int t_l = tid >> 6, lane = tid & 63, blo = lane & 15, grp = lane >> 4;
  int t = t0 + t_l;
  if (t >= S) return;
#pragma unroll
  for (int kh = 0; kh < 2; ++kh) {
    const f32x4* src = (const f32x4*)&xs[t_l][blo][kh * 32 + grp * 8];
    f32x4 a0 = src[0], a1 = src[1];
    bf16x8 hi, lo;
#pragma unroll
    for (int e = 0; e < 4; ++e) {
      unsigned h0 = bf16_rne(a0[e]);
      hi[e] = (short)h0;
      lo[e] = (short)bf16_rne(a0[e] - __uint_as_float(h0 << 16));
      unsigned h1 = bf16_rne(a1[e]);
      hi[e + 4] = (short)h1;
      lo[e + 4] = (short)bf16_rne(a1[e] - __uint_as_float(h1 << 16));
    }
    u16* dst = Xf + (size_t)(bt * S + t) * 2048 + (size_t)kh * 1024 + lane * 8;
    *(bf16x8*)dst = hi;
    *(bf16x8*)(dst + 512) = lo;
  }
}

// ---------------- MFMA bidirectional GRU, register-local gates ----------------
// block = (bt: 16 batches, dir). 4 waves; wave w owns gate tiles {w, 4+w, 8+w}
// = r/z/n rows for j in [16w,16w+16). C-fragment (col=batch=lane&15, row=4*grp+u)
// hands each thread exactly its own 4 h-units' gates -> no gate LDS round-trip.
// h exchanged via double-buffered LDS; ONE barrier per step. 3xbf16 split for accuracy.
__global__ __launch_bounds__(256, 1) void kgru3(
    const u16* __restrict__ Xf, int S,
    const float* __restrict__ wih_f, const float* __restrict__ whh_f,
    const float* __restrict__ bih_f, const float* __restrict__ bhh_f,
    const float* __restrict__ wih_b, const float* __restrict__ whh_b,
    const float* __restrict__ bih_b, const float* __restrict__ bhh_b,
    u16* __restrict__ g) {
  __shared__ u16 Hhi[2][16][72];
  __shared__ u16 Hlo[2][16][72];
  int tid = threadIdx.x;
  int w = tid >> 6, lane = tid & 63, blo = lane & 15, grp = lane >> 4;
  int bt = blockIdx.x, dir = blockIdx.y;
  const float* wih = dir ? wih_b : wih_f;
  const float* whh = dir ? whh_b : whh_f;
  const float* bih = dir ? bih_b : bih_f;
  const float* bhh = dir ? bhh_b : bhh_f;

  // zero h buffer 0 (read by step 0)
  for (int idx = tid; idx < 16 * 72; idx += 256) {
    ((u16*)Hhi[0])[idx] = 0;
    ((u16*)Hlo[0])[idx] = 0;
  }

  // weight A-fragments: gate gi in {r,z,n} -> tile gi*4+w; row k = tile*16 + blo,
  // k-elems j = kh*32 + grp*8 + e
  bf16x8 Wih_hi[3][2], Wih_lo[3][2], Whh_hi[3][2], Whh_lo[3][2];
#pragma unroll
  for (int gi = 0; gi < 3; ++gi) {
    int k = (gi * 4 + w) * 16 + blo;
#pragma unroll
    for (int kh = 0; kh < 2; ++kh) {
      int j0 = kh * 32 + grp * 8;
#pragma unroll
      for (int m = 0; m < 2; ++m) {
        const float* src = (m ? whh : wih) + (size_t)k * 64 + j0;
        f32x4 a0 = *(const f32x4*)src;
        f32x4 a1 = *(const f32x4*)(src + 4);
        bf16x8 hi, lo;
#pragma unroll
        for (int e = 0; e < 4; ++e) {
          unsigned h0 = bf16_rne(a0[e]);
          hi[e] = (short)h0;
          lo[e] = (short)bf16_rne(a0[e] - __uint_as_float(h0 << 16));
          unsigned h1 = bf16_rne(a1[e]);
          hi[e + 4] = (short)h1;
          lo[e + 4] = (short)bf16_rne(a1[e] - __uint_as_float(h1 << 16));
        }
        if (m) {
          Whh_hi[gi][kh] = hi;
          Whh_lo[gi][kh] = lo;
        } else {
          Wih_hi[gi][kh] = hi;
          Wih_lo[gi][kh] = lo;
        }
      }
    }
  }
  // bias C-init: rows (gi*4+w)*16 + 4*grp + u
  f32x4 bI[3], bH[3];
#pragma unroll
  for (int gi = 0; gi < 3; ++gi) {
    int k0 = (gi * 4 + w) * 16 + 4 * grp;
    bI[gi] = *(const f32x4*)(bih + k0);
    bH[gi] = *(const f32x4*)(bhh + k0);
  }

  float ho[4] = {0.f, 0.f, 0.f, 0.f};
  int j0q = 16 * w + 4 * grp;
  const u16* xbase = Xf + (size_t)bt * S * 2048 + lane * 8;

  // 3 rotating x buffers: prefetch 2 steps ahead to cover HBM latency
  bf16x8 xA[4], xB[4], xC[4];
  {
    int tr0 = dir ? (S - 1) : 0;
    const u16* xp = xbase + (size_t)tr0 * 2048;
    xA[0] = *(const bf16x8*)(xp);
    xA[1] = *(const bf16x8*)(xp + 512);
    xA[2] = *(const bf16x8*)(xp + 1024);
    xA[3] = *(const bf16x8*)(xp + 1536);
    if (S > 1) {
      int tr1 = dir ? (S - 2) : 1;
      const u16* xq = xbase + (size_t)tr1 * 2048;
      xB[0] = *(const bf16x8*)(xq);
      xB[1] = *(const bf16x8*)(xq + 512);
      xB[2] = *(const bf16x8*)(xq + 1024);
      xB[3] = *(const bf16x8*)(xq + 1536);
    }
  }
  block_sync_lds();

  int p = 0;
  auto step = [&](bf16x8(&cur)[4], bf16x8(&nx2)[4], int t) {
    // prefetch x for t+2 (stays in flight across the barrier)
    if (t + 2 < S) {
      int trn = dir ? (S - 3 - t) : (t + 2);
      const u16* xp = xbase + (size_t)trn * 2048;
      nx2[0] = *(const bf16x8*)(xp);
      nx2[1] = *(const bf16x8*)(xp + 512);
      nx2[2] = *(const bf16x8*)(xp + 1024);
      nx2[3] = *(const bf16x8*)(xp + 1536);
    }
    // issue h fragment reads early; ax MFMAs below don't depend on them
    bf16x8 h0h = *(const bf16x8*)&Hhi[p][blo][grp * 8];
    bf16x8 h0l = *(const bf16x8*)&Hlo[p][blo][grp * 8];
    bf16x8 h1h = *(const bf16x8*)&Hhi[p][blo][32 + grp * 8];
    bf16x8 h1l = *(const bf16x8*)&Hlo[p][blo][32 + grp * 8];
    f32x4 axr = bI[0], axz = bI[1], axn = bI[2];
#pragma unroll
    for (int kh = 0; kh < 2; ++kh) {
      bf16x8 xh = cur[2 * kh], xl = cur[2 * kh + 1];
      axr = __builtin_amdgcn_mfma_f32_16x16x32_bf16(Wih_hi[0][kh], xh, axr, 0, 0, 0);
      axr = __builtin_amdgcn_mfma_f32_16x16x32_bf16(Wih_hi[0][kh], xl, axr, 0, 0, 0);
      axr = __builtin_amdgcn_mfma_f32_16x16x32_bf16(Wih_lo[0][kh], xh, axr, 0, 0, 0);
      axz = __builtin_amdgcn_mfma_f32_16x16x32_bf16(Wih_hi[1][kh], xh, axz, 0, 0, 0);
      axz = __builtin_amdgcn_mfma_f32_16x16x32_bf16(Wih_hi[1][kh], xl, axz, 0, 0, 0);
      axz = __builtin_amdgcn_mfma_f32_16x16x32_bf16(Wih_lo[1][kh], xh, axz, 0, 0, 0);
      axn = __builtin_amdgcn_mfma_f32_16x16x32_bf16(Wih_hi[2][kh], xh, axn, 0, 0, 0);
      axn = __builtin_amdgcn_mfma_f32_16x16x32_bf16(Wih_hi[2][kh], xl, axn, 0, 0, 0);
      axn = __builtin_amdgcn_mfma_f32_16x16x32_bf16(Wih_lo[2][kh], xh, axn, 0, 0, 0);
    }
    f32x4 ahr = bH[0], ahz = bH[1], ahn = bH[2];
#pragma unroll
    for (int kh = 0; kh < 2; ++kh) {
      bf16x8 hh = kh ? h1h : h0h, hl = kh ? h1l : h0l;
      ahr = __builtin_amdgcn_mfma_f32_16x16x32_bf16(Whh_hi[0][kh], hh, ahr, 0, 0, 0);
      ahr = __builtin_amdgcn_mfma_f32_16x16x32_bf16(Whh_hi[0][kh], hl, ahr, 0, 0, 0);
      ahr = __builtin_amdgcn_mfma_f32_16x16x32_bf16(Whh_lo[0][kh], hh, ahr, 0, 0, 0);
      ahz = __builtin_amdgcn_mfma_f32_16x16x32_bf16(Whh_hi[1][kh], hh, ahz, 0, 0, 0);
      ahz = __builtin_amdgcn_mfma_f32_16x16x32_bf16(Whh_hi[1][kh], hl, ahz, 0, 0, 0);
      ahz = __builtin_amdgcn_mfma_f32_16x16x32_bf16(Whh_lo[1][kh], hh, ahz, 0, 0, 0);
      ahn = __builtin_amdgcn_mfma_f32_16x16x32_bf16(Whh_hi[2][kh], hh, ahn, 0, 0, 0);
      ahn = __builtin_amdgcn_mfma_f32_16x16x32_bf16(Whh_hi[2][kh], hl, ahn, 0, 0, 0);
      ahn = __builtin_amdgcn_mfma_f32_16x16x32_bf16(Whh_lo[2][kh], hh, ahn, 0, 0, 0);
    }
    // gates entirely in registers
    u16 hi_u[4], lo_u[4];
#pragma unroll
    for (int u = 0; u < 4; ++u) {
      float r = sigm2(axr[u] + ahr[u]);
      float z = sigm2(axz[u] + ahz[u]);
      float n = tanh2(axn[u] + r * ahn[u]);
      float h = (1.f - z) * n + z * ho[u];
      ho[u] = h;
      unsigned hb = bf16_rne(h);
      hi_u[u] = (u16)hb;
      lo_u[u] = (u16)bf16_rne(h - __uint_as_float(hb << 16));
    }
    ushort4 h4;
    h4.x = hi_u[0]; h4.y = hi_u[1]; h4.z = hi_u[2]; h4.w = hi_u[3];
    ushort4 l4;
    l4.x = lo_u[0]; l4.y = lo_u[1]; l4.z = lo_u[2]; l4.w = lo_u[3];
    int tr = dir ? (S - 1 - t) : t;
    *(ushort4*)(g + ((size_t)(bt * 16 + blo) * S + tr) * 128 + dir * 64 + j0q) = h4;
    *(ushort4*)&Hhi[p ^ 1][blo][j0q] = h4;
    *(ushort4*)&Hlo[p ^ 1][blo][j0q] = l4;
    block_sync_lds();
    p ^= 1;
  };

  for (int t = 0; t < S; t += 3) {
    step(xA, xC, t);
    if (t + 1 < S) step(xB, xA, t + 1);
    if (t + 2 < S) step(xC, xB, t + 2);
  }
}

// ---------------- BN(train) stats -> per-channel scale/shift ----------------
__global__ __launch_bounds__(256) void kbn(const u16* __restrict__ g, int S,
                    const float* __restrict__ gamma, const float* __restrict__ beta,
                    float* __restrict__ sd) {
  int t = blockIdx.x, tid = threadIdx.x;
  float s = 0.f, s2 = 0.f;
  for (int unit = tid; unit < 32768; unit += 256) {
    int b = unit >> 5, c4 = (unit & 31) * 4;
    ushort4 u = *(const ushort4*)(g + ((size_t)b * S + t) * 128 + c4);
    float v0 = __uint_as_float((unsigned)u.x << 16);
    float v1 = __uint_as_float((unsigned)u.y << 16);
    float v2 = __uint_as_float((unsigned)u.z << 16);
    float v3 = __uint_as_float((unsigned)u.w << 16);
    s += v0 + v1 + v2 + v3;
    s2 += v0 * v0 + v1 * v1 + v2 * v2 + v3 * v3;
  }
  __shared__ float rs[256], rq[256];
  rs[tid] = s;
  rq[tid] = s2;
  __syncthreads();
  for (int off = 128; off; off >>= 1) {
    if (tid < off) {
      rs[tid] += rs[tid + off];
      rq[tid] += rq[tid + off];
    }
    __syncthreads();
  }
  if (tid == 0) {
    float inv_n = 1.f / (float)(B_ * C_);
    float m = rs[0] * inv_n;
    float var = rq[0] * inv_n - m * m;
    float inv = 1.f / sqrtf(var + 1e-5f);
    float sc = gamma[t] * inv;
    sd[2 * t] = sc;
    sd[2 * t + 1] = beta[t] - m * sc;
  }
}

// -------- M_T[o][t][c] = sum_t2 W1[o][16384 + c*128 + t2] * linT_w[t2][t] --------
__global__ __launch_bounds__(256) void kMT(const float* __restrict__ W1, const float* __restrict__ lw,
                    float* __restrict__ MT) {
  __shared__ float W1s[128][129];
  __shared__ float ls[128][32];
  int o = blockIdx.x, t0 = blockIdx.y * 32, tid = threadIdx.x;
  const float* Wo = W1 + (size_t)o * 32768 + 16384;
  for (int idx = tid; idx < 16384; idx += 256) W1s[idx >> 7][idx & 127] = Wo[idx];
  for (int idx = tid; idx < 4096; idx += 256)
    ls[idx >> 5][idx & 31] = lw[(idx >> 5) * 256 + t0 + (idx & 31)];
  __syncthreads();
  int c = tid & 127, th = tid >> 7;
  float acc[16];
#pragma unroll
  for (int q = 0; q < 16; ++q) acc[q] = 0.f;
  for (int t2 = 0; t2 < 128; ++t2) {
    float w = W1s[c][t2];
#pragma unroll
    for (int q = 0; q < 16; ++q) acc[q] += w * ls[t2][th + 2 * q];
  }
  float* Mo = MT + (size_t)o * 32768;
#pragma unroll
  for (int q = 0; q < 16; ++q) Mo[(t0 + th + 2 * q) * 128 + c] = acc[q];
}

// -------- M_F[o][f][c] = sum_t2 W1[o][c*128 + t2] * linF_w[t2][f] --------
__global__ __launch_bounds__(256) void kMF(const float* __restrict__ W1, const float* __restrict__ lw,
                    float* __restrict__ MF) {
  __shared__ float W1s[128][129];
  __shared__ float ls[128][8];
  int o = blockIdx.x, tid = threadIdx.x;
  const float* Wo = W1 + (size_t)o * 32768;
  for (int idx = tid; idx < 16384; idx += 256) W1s[idx >> 7][idx & 127] = Wo[idx];
  for (int idx = tid; idx < 640; idx += 256) ls[idx / 5][idx % 5] = lw[idx];
  __syncthreads();
  int c = tid & 127, fh = tid >> 7;
  float acc[3] = {0.f, 0.f, 0.f};
  for (int t2 = 0; t2 < 128; ++t2) {
    float w = W1s[c][t2];
#pragma unroll
    for (int q = 0; q < 3; ++q) {
      int f = fh + 2 * q;
      if (f < 5) acc[q] += w * ls[t2][f];
    }
  }
#pragma unroll
  for (int q = 0; q < 3; ++q) {
    int f = fh + 2 * q;
    if (f < 5) MF[(size_t)o * 640 + f * 128 + c] = acc[q];
  }
}

// -------- c0[o] = lin1_b[o] + sum_idx W1F*linF_b + W1T*linT_b --------
__global__ __launch_bounds__(256) void kc0(const float* __restrict__ W1, const float* __restrict__ lFb,
                    const float* __restrict__ lTb, const float* __restrict__ l1b,
                    float* __restrict__ c0) {
  int o = blockIdx.x, tid = threadIdx.x;
  const float* Wo = W1 + (size_t)o * 32768;
  float s = 0.f;
  for (int idx = tid; idx < 16384; idx += 256) {
    int t2 = idx & 127;
    s += Wo[idx] * lFb[t2] + Wo[16384 + idx] * lTb[t2];
  }
  __shared__ float rs[256];
  rs[tid] = s;
  __syncthreads();
  for (int off = 128; off; off >>= 1) {
    if (tid < off) rs[tid] += rs[tid + off];
    __syncthreads();
  }
  if (tid == 0) c0[o] = l1b[o] + rs[0];
}

// -------- partial[slot][b][o] = sum_{t in chunk, c} (g*s_t+d_t) * M[o][t][c] --------
__global__ __launch_bounds__(256) void kchunk(const u16* __restrict__ g, int S, int nt,
                       const float* __restrict__ sd, const float* __restrict__ M,
                       float* __restrict__ part, int slot0) {
  __shared__ float gs[32][132];
  __shared__ float Ms[64][132];
  int tid = threadIdx.x;
  int b0 = blockIdx.x * 32;
  int t0 = blockIdx.y * nt;
  int slot = slot0 + blockIdx.y;
  int ot = tid & 31, bt = tid >> 5;
  float acc[4][2];
#pragma unroll
  for (int i = 0; i < 4; ++i) {
    acc[i][0] = 0.f;
    acc[i][1] = 0.f;
  }
  for (int t = t0; t < t0 + nt; ++t) {
    __syncthreads();
    float sc = sd[2 * t], dd = sd[2 * t + 1];
    for (int idx = tid; idx < 1024; idx += 256) {
      int bb = idx >> 5, c4 = (idx & 31) * 4;
      ushort4 u = *(const ushort4*)(g + ((size_t)(b0 + bb) * S + t) * 128 + c4);
      gs[bb][c4 + 0] = __uint_as_float((unsigned)u.x << 16) * sc + dd;
      gs[bb][c4 + 1] = __uint_as_float((unsigned)u.y << 16) * sc + dd;
      gs[bb][c4 + 2] = __uint_as_float((unsigned)u.z << 16) * sc + dd;
      gs[bb][c4 + 3] = __uint_as_float((unsigned)u.w << 16) * sc + dd;
    }
    for (int idx = tid; idx < 2048; idx += 256) {
      int o = idx >> 5, c4 = (idx & 31) * 4;
      *(float4*)&Ms[o][c4] = *(const float4*)(M + ((size_t)o * S + t) * 128 + c4);
    }
    __syncthreads();
    for (int c = 0; c < 128; c += 4) {
      f32x4 m0 = *(const f32x4*)&Ms[ot][c];
      f32x4 m1 = *(const f32x4*)&Ms[ot + 32][c];
#pragma unroll
      for (int i = 0; i < 4; ++i) {
        f32x4 gv = *(const f32x4*)&gs[bt * 4 + i][c];
        acc[i][0] += gv[0] * m0[0] + gv[1] * m0[1] + gv[2] * m0[2] + gv[3] * m0[3];
        acc[i][1] += gv[0] * m1[0] + gv[1] * m1[1] + gv[2] * m1[2] + gv[3] * m1[3];
      }
    }
  }
#pragma unroll
  for (int i = 0; i < 4; ++i) {
    part[((size_t)slot * 1024 + b0 + bt * 4 + i) * 64 + ot] = acc[i][0];
    part[((size_t)slot * 1024 + b0 + bt * 4 + i) * 64 + ot + 32] = acc[i][1];
  }
}

// -------- finalize: y = leaky(sum partials + c0); out = y @ lin2^T + b2 --------
__global__ __launch_bounds__(64) void kfin(const float* __restrict__ part, const float* __restrict__ c0,
                     const float* __restrict__ l2w, const float* __restrict__ l2b,
                     float* __restrict__ outp) {
  int b = blockIdx.x, o = threadIdx.x;
  float y = c0[o];
  for (int s = 0; s < 17; ++s) y += part[((size_t)s * 1024 + b) * 64 + o];
  y = leaky(y);
  __shared__ float a[64];
  a[o] = y;
  __syncthreads();
  if (o < 3) {
    float r = l2b[o];
    for (int j = 0; j < 64; ++j) r += l2w[o * 64 + j] * a[j];
    outp[b * 3 + o] = r;
  }
}

extern "C" void kernel_launch(void* const* d_in, const int* in_sizes, int n_in,
                              void* d_out, int out_size, void* d_ws, size_t ws_size,
                              hipStream_t stream) {
  const float* x_T = (const float*)d_in[0];
  const float* x_F = (const float*)d_in[1];
  const float* A = (const float*)d_in[2];
  const float* gcnw_F = (const float*)d_in[3];
  const float* gFwih_f = (const float*)d_in[4];
  const float* gFwhh_f = (const float*)d_in[5];
  const float* gFbih_f = (const float*)d_in[6];
  const float* gFbhh_f = (const float*)d_in[7];
  const float* gFwih_b = (const float*)d_in[8];
  const float* gFwhh_b = (const float*)d_in[9];
  const float* gFbih_b = (const float*)d_in[10];
  const float* gFbhh_b = (const float*)d_in[11];
  const float* bnFg = (const float*)d_in[12];
  const float* bnFb = (const float*)d_in[13];
  const float* gcnw_T = (const float*)d_in[14];
  const float* gTwih_f = (const float*)d_in[15];
  const float* gTwhh_f = (const float*)d_in[16];
  const float* gTbih_f = (const float*)d_in[17];
  const float* gTbhh_f = (const float*)d_in[18];
  const float* gTwih_b = (const float*)d_in[19];
  const float* gTwhh_b = (const float*)d_in[20];
  const float* gTbih_b = (const float*)d_in[21];
  const float* gTbhh_b = (const float*)d_in[22];
  const float* bnTg = (const float*)d_in[23];
  const float* bnTb = (const float*)d_in[24];
  const float* linF_w = (const float*)d_in[25];
  const float* linF_b = (const float*)d_in[26];
  const float* linT_w = (const float*)d_in[27];
  const float* linT_b = (const float*)d_in[28];
  const float* lin1_w = (const float*)d_in[29];
  const float* lin1_b = (const float*)d_in[30];
  const float* lin2_w = (const float*)d_in[31];
  const float* lin2_b = (const float*)d_in[32];

  char* w8 = (char*)d_ws;
  size_t off = 0;
  auto take = [&](size_t bytes) {
    void* p = w8 + off;
    off += (bytes + 255) & ~(size_t)255;
    return p;
  };
  float* Hn = (float*)take((size_t)1024 * 4096 * 4);
  float* XpT = (float*)take((size_t)1024 * 256 * 64 * 4);
  float* XpF = (float*)take((size_t)1024 * 5 * 64 * 4);
  u16* XfT = (u16*)take((size_t)64 * 256 * 2048 * 2);
  u16* XfF = (u16*)take((size_t)64 * 5 * 2048 * 2);
  u16* gT = (u16*)take((size_t)1024 * 256 * 128 * 2);
  u16* gF = (u16*)take((size_t)1024 * 5 * 128 * 2);
  float* sdT = (float*)take(512 * 4);
  float* sdF = (float*)take(16 * 4);
  float* MT = (float*)take((size_t)64 * 256 * 128 * 4);
  float* MF = (float*)take((size_t)64 * 5 * 128 * 4);
  float* c0 = (float*)take(64 * 4);
  float* part = (float*)take((size_t)17 * 1024 * 64 * 4);

  knorm<<<1024, 64, 0, stream>>>(A, Hn);
  kxc<<<dim3(1024, 4), 256, 0, stream>>>(Hn, x_T, gcnw_T, XpT, 256);
  kxc<<<dim3(1024, 1), 256, 0, stream>>>(Hn, x_F, gcnw_F, XpF, 5);
  kxq<<<dim3(64, 64), 256, 0, stream>>>(XpT, 256, XfT);
  kxq<<<dim3(64, 2), 256, 0, stream>>>(XpF, 5, XfF);
  kgru3<<<dim3(64, 2), 256, 0, stream>>>(XfT, 256, gTwih_f, gTwhh_f, gTbih_f, gTbhh_f,
                                         gTwih_b, gTwhh_b, gTbih_b, gTbhh_b, gT);
  kgru3<<<dim3(64, 2), 256, 0, stream>>>(XfF, 5, gFwih_f, gFwhh_f, gFbih_f, gFbhh_f,
                                         gFwih_b, gFwhh_b, gFbih_b, gFbhh_b, gF);
  kbn<<<256, 256, 0, stream>>>(gT, 256, bnTg, bnTb, sdT);
  kbn<<<5, 256, 0, stream>>>(gF, 5, bnFg, bnFb, sdF);
  kMT<<<dim3(64, 8), 256, 0, stream>>>(lin1_w, linT_w, MT);
  kMF<<<64, 256, 0, stream>>>(lin1_w, linF_w, MF);
  kc0<<<64, 256, 0, stream>>>(lin1_w, linF_b, linT_b, lin1_b, c0);
  kchunk<<<dim3(32, 16), 256, 0, stream>>>(gT, 256, 16, sdT, MT, part, 0);
  kchunk<<<dim3(32, 1), 256, 0, stream>>>(gF, 5, 5, sdF, MF, part, 16);
  kfin<<<1024, 64, 0, stream>>>(part, c0, lin2_w, lin2_b, (float*)d_out);
}